// Round 2
// baseline (668.850 us; speedup 1.0000x reference)
//
#include <hip/hip_runtime.h>

// Problem dims (reference): N=20000, E=640000, D_IN=256, HID=128, HEADS=4,
// D_OUT=128, R=32. Per harness doc, dtypes follow the REFERENCE: all float
// tensors are fp32 (float*), ints are int32. Output is fp32.

#define D_IN   256
#define HID1   512   // HEADS*HID
#define NHEADS 4
#define CH1    128
#define DOUT   128
#define NREL   32
#define NEG_SLOPE 0.2f

static __device__ __forceinline__ float lrelu(float x) {
  return x > 0.f ? x : NEG_SLOPE * x;
}

// ---- CSR build ------------------------------------------------------------
__global__ void count_kernel(const int* __restrict__ src, const int* __restrict__ dst,
                             const int* __restrict__ et, int* __restrict__ counts,
                             int* __restrict__ deg, int E) {
  int e = blockIdx.x * 256 + threadIdx.x;
  if (e >= E) return;
  atomicAdd(&counts[(size_t)src[e] * NREL + et[e]], 1);
  atomicAdd(&deg[dst[e]], 1);
}

// single-block exclusive scan over n (=20000) elements, writes n+1 offsets
__global__ void exscan_kernel(const int* __restrict__ in, int* __restrict__ out, int n) {
  __shared__ int buf[1024];
  __shared__ int carry_s;
  if (threadIdx.x == 0) carry_s = 0;
  __syncthreads();
  for (int base = 0; base < n; base += 1024) {
    int i = base + (int)threadIdx.x;
    int v = (i < n) ? in[i] : 0;
    buf[threadIdx.x] = v;
    __syncthreads();
    for (int off = 1; off < 1024; off <<= 1) {
      int t = (threadIdx.x >= (unsigned)off) ? buf[threadIdx.x - off] : 0;
      __syncthreads();
      buf[threadIdx.x] += t;
      __syncthreads();
    }
    int carry = carry_s;
    int incl = buf[threadIdx.x];
    if (i < n) out[i] = carry + incl - v;
    __syncthreads();
    if (threadIdx.x == 0) carry_s = carry + buf[1023];
    __syncthreads();
  }
  if (threadIdx.x == 0) out[n] = carry_s;
}

__global__ void scatter_kernel(const int* __restrict__ src, const int* __restrict__ dst,
                               const int* __restrict__ offsets, int* __restrict__ cursor,
                               int* __restrict__ csr_src, int E) {
  int e = blockIdx.x * 256 + threadIdx.x;
  if (e >= E) return;
  int d = dst[e];
  int pos = offsets[d] + atomicAdd(&cursor[d], 1);
  csr_src[pos] = src[e];
}

// ---- relational injection: x_mod[n] = x[n] + sum_r counts[n][r]*rel[r] ----
__global__ void xmod_kernel(const float* __restrict__ x,
                            const int* __restrict__ counts,
                            const float* __restrict__ rel,
                            float* __restrict__ x_mod, int n_nodes) {
  __shared__ int cnt[NREL];
  int node = blockIdx.x;
  if (threadIdx.x < NREL) cnt[threadIdx.x] = counts[(size_t)node * NREL + threadIdx.x];
  __syncthreads();
  int k = threadIdx.x;  // blockDim.x == 256 == D_IN
  float v = x[(size_t)node * D_IN + k];
  for (int r = 0; r < NREL; ++r) {
    int c = cnt[r];
    if (c) v += (float)c * rel[r * D_IN + k];  // wave-uniform branch
  }
  x_mod[(size_t)node * D_IN + k] = v;
}

// ---- fp32 tiled GEMM: C[M,N] = A[M,K] * B[K,N] ---------------------------
__global__ __launch_bounds__(256) void gemm_kernel(
    const float* __restrict__ A, const float* __restrict__ B,
    float* __restrict__ C, int M, int N, int K) {
  __shared__ float As[16][65];  // [k][m], +1 pad kills write conflicts
  __shared__ float Bs[16][64];  // [k][n]
  int tid = threadIdx.x;
  int tx = tid & 15, ty = tid >> 4;
  int m0 = blockIdx.y * 64, n0 = blockIdx.x * 64;
  int a_m = tid >> 2, a_k = (tid & 3) << 2;
  int b_k = tid >> 4, b_n = (tid & 15) << 2;
  float acc[4][4] = {{0.f}};
  for (int k0 = 0; k0 < K; k0 += 16) {
    float4 av = make_float4(0.f, 0.f, 0.f, 0.f);
    int gm = m0 + a_m;
    if (gm < M) av = *(const float4*)(A + (size_t)gm * K + k0 + a_k);
    As[a_k + 0][a_m] = av.x; As[a_k + 1][a_m] = av.y;
    As[a_k + 2][a_m] = av.z; As[a_k + 3][a_m] = av.w;
    float4 bv = *(const float4*)(B + (size_t)(k0 + b_k) * N + n0 + b_n);
    Bs[b_k][b_n + 0] = bv.x; Bs[b_k][b_n + 1] = bv.y;
    Bs[b_k][b_n + 2] = bv.z; Bs[b_k][b_n + 3] = bv.w;
    __syncthreads();
#pragma unroll
    for (int kk = 0; kk < 16; ++kk) {
      float a[4], b[4];
#pragma unroll
      for (int i = 0; i < 4; ++i) a[i] = As[kk][ty * 4 + i];
#pragma unroll
      for (int j = 0; j < 4; ++j) b[j] = Bs[kk][tx * 4 + j];
#pragma unroll
      for (int i = 0; i < 4; ++i)
#pragma unroll
        for (int j = 0; j < 4; ++j) acc[i][j] = fmaf(a[i], b[j], acc[i][j]);
    }
    __syncthreads();
  }
#pragma unroll
  for (int i = 0; i < 4; ++i) {
    int gm = m0 + ty * 4 + i;
    if (gm < M)
      *(float4*)(C + (size_t)gm * N + n0 + tx * 4) =
          make_float4(acc[i][0], acc[i][1], acc[i][2], acc[i][3]);
  }
}

// ---- attention logits -----------------------------------------------------
__global__ void alpha1_kernel(const float* __restrict__ h1,
                              const float* __restrict__ att_s,
                              const float* __restrict__ att_d,
                              float* __restrict__ as1, float* __restrict__ ad1,
                              int n_nodes) {
  int node = blockIdx.x;
  int head = threadIdx.x >> 6, lane = threadIdx.x & 63;
  const float* hp = h1 + (size_t)node * HID1 + head * CH1;
  float v0 = hp[lane], v1 = hp[lane + 64];
  float s = v0 * att_s[head * CH1 + lane] + v1 * att_s[head * CH1 + lane + 64];
  float d = v0 * att_d[head * CH1 + lane] + v1 * att_d[head * CH1 + lane + 64];
  for (int off = 32; off; off >>= 1) { s += __shfl_xor(s, off); d += __shfl_xor(d, off); }
  if (lane == 0) { as1[(size_t)node * NHEADS + head] = s; ad1[(size_t)node * NHEADS + head] = d; }
}

__global__ void alpha2_kernel(const float* __restrict__ t2,
                              const float* __restrict__ att_s,
                              const float* __restrict__ att_d,
                              float* __restrict__ as2, float* __restrict__ ad2,
                              int n_nodes) {
  int node = blockIdx.x * 4 + (threadIdx.x >> 6);
  int lane = threadIdx.x & 63;
  if (node >= n_nodes) return;
  const float* tp = t2 + (size_t)node * DOUT;
  float v0 = tp[lane], v1 = tp[lane + 64];
  float s = v0 * att_s[lane] + v1 * att_s[lane + 64];
  float d = v0 * att_d[lane] + v1 * att_d[lane + 64];
  for (int off = 32; off; off >>= 1) { s += __shfl_xor(s, off); d += __shfl_xor(d, off); }
  if (lane == 0) { as2[node] = s; ad2[node] = d; }
}

// ---- layer-1 segment softmax + aggregate + bias + ELU ---------------------
// one block per dst node; wave w handles head w; lanes split 128 channels
__global__ void aggregate1_kernel(const float* __restrict__ h1,
                                  const float* __restrict__ as1,
                                  const float* __restrict__ ad1,
                                  const int* __restrict__ offsets,
                                  const int* __restrict__ csr_src,
                                  const float* __restrict__ bias,
                                  float* __restrict__ h2, int n_nodes) {
  int node = blockIdx.x;
  int head = threadIdx.x >> 6, lane = threadIdx.x & 63;
  int lo = offsets[node], hi = offsets[node + 1];
  float ad = ad1[(size_t)node * NHEADS + head];
  float e_self = lrelu(as1[(size_t)node * NHEADS + head] + ad);
  float m = e_self;
  for (int j = lo + lane; j < hi; j += 64)
    m = fmaxf(m, lrelu(as1[(size_t)csr_src[j] * NHEADS + head] + ad));
  for (int off = 32; off; off >>= 1) m = fmaxf(m, __shfl_xor(m, off));
  float acc0 = 0.f, acc1 = 0.f, denom = 0.f;
  for (int j = lo; j < hi; ++j) {
    int s = csr_src[j];
    float w = __expf(lrelu(as1[(size_t)s * NHEADS + head] + ad) - m);
    const float* hp = h1 + (size_t)s * HID1 + head * CH1;
    acc0 += w * hp[lane]; acc1 += w * hp[lane + 64]; denom += w;
  }
  { // self loop
    float w = __expf(e_self - m);
    const float* hp = h1 + (size_t)node * HID1 + head * CH1;
    acc0 += w * hp[lane]; acc1 += w * hp[lane + 64]; denom += w;
  }
  float inv = 1.f / (denom + 1e-16f);
  float v0 = acc0 * inv + bias[head * CH1 + lane];
  float v1 = acc1 * inv + bias[head * CH1 + lane + 64];
  v0 = v0 > 0.f ? v0 : expm1f(v0);  // ELU
  v1 = v1 > 0.f ? v1 : expm1f(v1);
  h2[(size_t)node * HID1 + head * CH1 + lane] = v0;
  h2[(size_t)node * HID1 + head * CH1 + lane + 64] = v1;
}

// ---- layer-2 (1 head, 128 ch): softmax + aggregate + bias -> fp32 out -----
__global__ void aggregate2_kernel(const float* __restrict__ t2,
                                  const float* __restrict__ as2,
                                  const float* __restrict__ ad2,
                                  const int* __restrict__ offsets,
                                  const int* __restrict__ csr_src,
                                  const float* __restrict__ bias,
                                  float* __restrict__ out, int n_nodes) {
  int node = blockIdx.x * 4 + (threadIdx.x >> 6);
  int lane = threadIdx.x & 63;
  if (node >= n_nodes) return;
  int lo = offsets[node], hi = offsets[node + 1];
  float ad = ad2[node];
  float e_self = lrelu(as2[node] + ad);
  float m = e_self;
  for (int j = lo + lane; j < hi; j += 64)
    m = fmaxf(m, lrelu(as2[csr_src[j]] + ad));
  for (int off = 32; off; off >>= 1) m = fmaxf(m, __shfl_xor(m, off));
  float acc0 = 0.f, acc1 = 0.f, denom = 0.f;
  for (int j = lo; j < hi; ++j) {
    int s = csr_src[j];
    float w = __expf(lrelu(as2[s] + ad) - m);
    const float* tp = t2 + (size_t)s * DOUT;
    acc0 += w * tp[lane]; acc1 += w * tp[lane + 64]; denom += w;
  }
  {
    float w = __expf(e_self - m);
    const float* tp = t2 + (size_t)node * DOUT;
    acc0 += w * tp[lane]; acc1 += w * tp[lane + 64]; denom += w;
  }
  float inv = 1.f / (denom + 1e-16f);
  out[(size_t)node * DOUT + lane]      = acc0 * inv + bias[lane];
  out[(size_t)node * DOUT + lane + 64] = acc1 * inv + bias[lane + 64];
}

extern "C" void kernel_launch(void* const* d_in, const int* in_sizes, int n_in,
                              void* d_out, int out_size, void* d_ws, size_t ws_size,
                              hipStream_t stream) {
  const float* x     = (const float*)d_in[0];
  const int* ei      = (const int*)d_in[1];
  const int* etype   = (const int*)d_in[2];
  const float* rel   = (const float*)d_in[3];
  const float* W1    = (const float*)d_in[4];
  const float* at_s1 = (const float*)d_in[5];
  const float* at_d1 = (const float*)d_in[6];
  const float* b1    = (const float*)d_in[7];
  const float* W2    = (const float*)d_in[8];
  const float* at_s2 = (const float*)d_in[9];
  const float* at_d2 = (const float*)d_in[10];
  const float* b2v   = (const float*)d_in[11];
  float* out         = (float*)d_out;

  const int N = in_sizes[0] / D_IN;  // 20000
  const int E = in_sizes[2];         // 640000
  const int* srcv = ei;
  const int* dstv = ei + E;

  // workspace carve; t2 aliases x_mod (disjoint lifetimes) to trim peak
  char* p = (char*)d_ws;
  auto carve = [&](size_t bytes) -> char* {
    char* r = p; p += (bytes + 255) & ~(size_t)255; return r;
  };
  int*   counts  = (int*)carve((size_t)N * NREL * 4);
  int*   deg     = (int*)carve((size_t)N * 4);
  int*   offsets = (int*)carve(((size_t)N + 1) * 4);
  int*   cursor  = (int*)carve((size_t)N * 4);
  int*   csr_src = (int*)carve((size_t)E * 4);
  float* as1     = (float*)carve((size_t)N * NHEADS * 4);
  float* ad1     = (float*)carve((size_t)N * NHEADS * 4);
  float* as2     = (float*)carve((size_t)N * 4);
  float* ad2     = (float*)carve((size_t)N * 4);
  float* x_mod   = (float*)carve((size_t)N * D_IN * 4);
  float* t2      = x_mod;  // alias: x_mod dead after gemm1; t2 is N*DOUT <= N*D_IN
  float* h1      = (float*)carve((size_t)N * HID1 * 4);
  float* h2      = (float*)carve((size_t)N * HID1 * 4);

  hipMemsetAsync(counts, 0, (size_t)N * NREL * 4, stream);
  hipMemsetAsync(deg, 0, (size_t)N * 4, stream);
  hipMemsetAsync(cursor, 0, (size_t)N * 4, stream);

  int eb = (E + 255) / 256;
  count_kernel<<<eb, 256, 0, stream>>>(srcv, dstv, etype, counts, deg, E);
  exscan_kernel<<<1, 1024, 0, stream>>>(deg, offsets, N);
  scatter_kernel<<<eb, 256, 0, stream>>>(srcv, dstv, offsets, cursor, csr_src, E);
  xmod_kernel<<<N, 256, 0, stream>>>(x, counts, rel, x_mod, N);
  gemm_kernel<<<dim3(HID1 / 64, (N + 63) / 64), 256, 0, stream>>>(x_mod, W1, h1, N, HID1, D_IN);
  alpha1_kernel<<<N, 256, 0, stream>>>(h1, at_s1, at_d1, as1, ad1, N);
  aggregate1_kernel<<<N, 256, 0, stream>>>(h1, as1, ad1, offsets, csr_src, b1, h2, N);
  gemm_kernel<<<dim3(DOUT / 64, (N + 63) / 64), 256, 0, stream>>>(h2, W2, t2, N, DOUT, HID1);
  alpha2_kernel<<<(N + 3) / 4, 256, 0, stream>>>(t2, at_s2, at_d2, as2, ad2, N);
  aggregate2_kernel<<<(N + 3) / 4, 256, 0, stream>>>(t2, as2, ad2, offsets, csr_src, b2v, out, N);
}

// Round 3
// 508.245 us; speedup vs baseline: 1.3160x; 1.3160x over previous
//
#include <hip/hip_runtime.h>

// N=20000, E=640000, D_IN=256, HID1=512 (4 heads x 128), D_OUT=128, R=32.
// fp32 inputs/outputs; internal h1/h2/t2/x_mod in bf16 (gather traffic + MFMA).

#define D_IN   256
#define HID1   512
#define NHEADS 4
#define CH1    128
#define DOUT   128
#define NREL   32
#define NEG_SLOPE 0.2f
#define M_PAD  20096   // 157*128, GEMM row padding

static __device__ __forceinline__ float b2f(unsigned short u) {
  union { unsigned int i; float f; } v; v.i = ((unsigned int)u) << 16; return v.f;
}
static __device__ __forceinline__ unsigned short f2b(float f) {
  union { float f; unsigned int i; } v; v.f = f;
  unsigned int x = v.i;
  return (unsigned short)((x + 0x7fffu + ((x >> 16) & 1u)) >> 16);
}
static __device__ __forceinline__ float lrelu(float x) {
  return x > 0.f ? x : NEG_SLOPE * x;
}

typedef __attribute__((ext_vector_type(8))) short bf16x8;
typedef __attribute__((ext_vector_type(4))) float f32x4;

// ---- degree / relation counting ------------------------------------------
__global__ void count_kernel(const int* __restrict__ src, const int* __restrict__ dst,
                             const int* __restrict__ et, int* __restrict__ counts,
                             int* __restrict__ deg, int E) {
  int e = blockIdx.x * 256 + threadIdx.x;
  if (e >= E) return;
  atomicAdd(&counts[(size_t)src[e] * NREL + et[e]], 1);
  atomicAdd(&deg[dst[e]], 1);
}

// ---- hierarchical exclusive scan (3 kernels, 1024 elems/block) ------------
__global__ void scan_local(const int* __restrict__ in, int* __restrict__ out,
                           int* __restrict__ bsum, int n) {
  __shared__ int wsum[4];
  int t = threadIdx.x;
  int base = blockIdx.x * 1024 + t * 4;
  int v0 = (base + 0 < n) ? in[base + 0] : 0;
  int v1 = (base + 1 < n) ? in[base + 1] : 0;
  int v2 = (base + 2 < n) ? in[base + 2] : 0;
  int v3 = (base + 3 < n) ? in[base + 3] : 0;
  int s = v0 + v1 + v2 + v3;
  int lane = t & 63, w = t >> 6;
  int sc = s;
  for (int off = 1; off < 64; off <<= 1) {
    int u = __shfl_up(sc, off);
    if (lane >= off) sc += u;
  }
  if (lane == 63) wsum[w] = sc;
  __syncthreads();
  int woff = 0;
  for (int i = 0; i < w; ++i) woff += wsum[i];
  int excl = woff + sc - s;
  if (base + 0 < n) out[base + 0] = excl;
  if (base + 1 < n) out[base + 1] = excl + v0;
  if (base + 2 < n) out[base + 2] = excl + v0 + v1;
  if (base + 3 < n) out[base + 3] = excl + v0 + v1 + v2;
  if (t == 255) bsum[blockIdx.x] = woff + sc;
}

__global__ void scan_blocks(int* __restrict__ bsum, int nb,
                            int* __restrict__ offsets, int n) {
  int t = threadIdx.x;  // 64 threads
  int v = (t < nb) ? bsum[t] : 0;
  int sc = v;
  for (int off = 1; off < 64; off <<= 1) {
    int u = __shfl_up(sc, off);
    if (t >= off) sc += u;
  }
  if (t < nb) bsum[t] = sc - v;
  if (t == 63) offsets[n] = sc;  // grand total (== E)
}

__global__ void scan_add(int* __restrict__ out, const int* __restrict__ bsum, int n) {
  int add = bsum[blockIdx.x];
  int i = blockIdx.x * 1024 + threadIdx.x * 4;
#pragma unroll
  for (int j = 0; j < 4; ++j)
    if (i + j < n) out[i + j] += add;
}

__global__ void scatter_kernel(const int* __restrict__ src, const int* __restrict__ dst,
                               const int* __restrict__ offsets, int* __restrict__ cursor,
                               int* __restrict__ csr_src, int E) {
  int e = blockIdx.x * 256 + threadIdx.x;
  if (e >= E) return;
  int d = dst[e];
  int pos = offsets[d] + atomicAdd(&cursor[d], 1);
  csr_src[pos] = src[e];
}

// ---- weight cast + transpose: W[R][C] fp32 -> WT[C][R] bf16 ---------------
__global__ void castT_kernel(const float* __restrict__ W, unsigned short* __restrict__ WT,
                             int R, int C) {
  int idx = blockIdx.x * 256 + threadIdx.x;
  if (idx >= R * C) return;
  int r = idx / C, c = idx % C;
  WT[(size_t)c * R + r] = f2b(W[idx]);
}

// ---- x_mod[n] = x[n] + sum_r counts[n][r]*rel[r]  (bf16 out) --------------
__global__ void xmod_kernel(const float* __restrict__ x,
                            const int* __restrict__ counts,
                            const float* __restrict__ rel,
                            unsigned short* __restrict__ x_modb, int n_nodes) {
  __shared__ int cnt[NREL];
  int node = blockIdx.x;
  if (threadIdx.x < NREL) cnt[threadIdx.x] = counts[(size_t)node * NREL + threadIdx.x];
  __syncthreads();
  int k = threadIdx.x;  // blockDim.x == 256 == D_IN
  float v = x[(size_t)node * D_IN + k];
  for (int r = 0; r < NREL; ++r) {
    int c = cnt[r];
    if (c) v += (float)c * rel[r * D_IN + k];
  }
  x_modb[(size_t)node * D_IN + k] = f2b(v);
}

// ---- bf16 MFMA GEMM: C[M_pad][N] = A[M_pad][K] * BT[N][K]^T  (bf16 out) ---
// 128x128 block tile, BK=32, 4 waves in 2x2, each wave 64x64 via 4x4 frags.
#define LDSW 40  // bf16 elems per LDS row (80B, 16B-aligned, 2-way-free banks)
__global__ __launch_bounds__(256) void mfma_gemm(
    const unsigned short* __restrict__ A, const unsigned short* __restrict__ BT,
    unsigned short* __restrict__ C, int M, int N, int K) {
  __shared__ __align__(16) unsigned short Asl[128 * LDSW];
  __shared__ __align__(16) unsigned short Bsl[128 * LDSW];
  int tid = threadIdx.x;
  int m0 = blockIdx.y * 128, n0 = blockIdx.x * 128;
  int lane = tid & 63, wid = tid >> 6;
  int wm = wid & 1, wn = wid >> 1;
  int l16 = lane & 15, quad = lane >> 4;

  f32x4 acc[4][4];
#pragma unroll
  for (int i = 0; i < 4; ++i)
#pragma unroll
    for (int j = 0; j < 4; ++j) acc[i][j] = (f32x4)(0.f);

  for (int k0 = 0; k0 < K; k0 += 32) {
#pragma unroll
    for (int p = 0; p < 2; ++p) {
      int lin = p * 256 + tid;      // 0..511
      int r = lin >> 2;             // tile row 0..127
      int seg = lin & 3;            // 16B segment
      int gr = m0 + r; gr = gr < M ? gr : M - 1;  // clamp (pad rows poisoned)
      uint4 va = *(const uint4*)(A + (size_t)gr * K + k0 + seg * 8);
      *(uint4*)(&Asl[r * LDSW + seg * 8]) = va;
      uint4 vb = *(const uint4*)(BT + (size_t)(n0 + r) * K + k0 + seg * 8);
      *(uint4*)(&Bsl[r * LDSW + seg * 8]) = vb;
    }
    __syncthreads();
    bf16x8 af[4], bfr[4];
#pragma unroll
    for (int mf = 0; mf < 4; ++mf)
      af[mf] = *(const bf16x8*)(&Asl[(wm * 64 + mf * 16 + l16) * LDSW + quad * 8]);
#pragma unroll
    for (int nf = 0; nf < 4; ++nf)
      bfr[nf] = *(const bf16x8*)(&Bsl[(wn * 64 + nf * 16 + l16) * LDSW + quad * 8]);
#pragma unroll
    for (int mf = 0; mf < 4; ++mf)
#pragma unroll
      for (int nf = 0; nf < 4; ++nf)
        acc[mf][nf] = __builtin_amdgcn_mfma_f32_16x16x32_bf16(af[mf], bfr[nf], acc[mf][nf], 0, 0, 0);
    __syncthreads();
  }
#pragma unroll
  for (int mf = 0; mf < 4; ++mf)
#pragma unroll
    for (int nf = 0; nf < 4; ++nf)
#pragma unroll
      for (int r = 0; r < 4; ++r) {
        int row = m0 + wm * 64 + mf * 16 + quad * 4 + r;
        int col = n0 + wn * 64 + nf * 16 + l16;
        C[(size_t)row * N + col] = f2b(acc[mf][nf][r]);
      }
}

// ---- attention logits -----------------------------------------------------
__global__ void alpha1_kernel(const unsigned short* __restrict__ h1b,
                              const float* __restrict__ att_s,
                              const float* __restrict__ att_d,
                              float* __restrict__ as1, float* __restrict__ ad1,
                              int n_nodes) {
  int node = blockIdx.x;
  int head = threadIdx.x >> 6, lane = threadIdx.x & 63;
  ushort2 uv = *(const ushort2*)(h1b + (size_t)node * HID1 + head * CH1 + 2 * lane);
  float v0 = b2f(uv.x), v1 = b2f(uv.y);
  float s = v0 * att_s[head * CH1 + 2 * lane] + v1 * att_s[head * CH1 + 2 * lane + 1];
  float d = v0 * att_d[head * CH1 + 2 * lane] + v1 * att_d[head * CH1 + 2 * lane + 1];
  for (int off = 32; off; off >>= 1) { s += __shfl_xor(s, off); d += __shfl_xor(d, off); }
  if (lane == 0) { as1[(size_t)node * NHEADS + head] = s; ad1[(size_t)node * NHEADS + head] = d; }
}

__global__ void alpha2_kernel(const unsigned short* __restrict__ t2b,
                              const float* __restrict__ att_s,
                              const float* __restrict__ att_d,
                              float* __restrict__ as2, float* __restrict__ ad2,
                              int n_nodes) {
  int node = blockIdx.x * 4 + (threadIdx.x >> 6);
  int lane = threadIdx.x & 63;
  if (node >= n_nodes) return;
  ushort2 uv = *(const ushort2*)(t2b + (size_t)node * DOUT + 2 * lane);
  float v0 = b2f(uv.x), v1 = b2f(uv.y);
  float s = v0 * att_s[2 * lane] + v1 * att_s[2 * lane + 1];
  float d = v0 * att_d[2 * lane] + v1 * att_d[2 * lane + 1];
  for (int off = 32; off; off >>= 1) { s += __shfl_xor(s, off); d += __shfl_xor(d, off); }
  if (lane == 0) { as2[node] = s; ad2[node] = d; }
}

// ---- layer-1 segment softmax + aggregate + bias + ELU (bf16 h2 out) -------
__global__ void aggregate1_kernel(const unsigned short* __restrict__ h1b,
                                  const float* __restrict__ as1,
                                  const float* __restrict__ ad1,
                                  const int* __restrict__ offsets,
                                  const int* __restrict__ csr_src,
                                  const float* __restrict__ bias,
                                  unsigned short* __restrict__ h2b, int n_nodes) {
  int node = blockIdx.x;
  int head = threadIdx.x >> 6, lane = threadIdx.x & 63;
  int lo = offsets[node], hi = offsets[node + 1];
  float ad = ad1[(size_t)node * NHEADS + head];
  float e_self = lrelu(as1[(size_t)node * NHEADS + head] + ad);
  float m = e_self;
  for (int j = lo + lane; j < hi; j += 64)
    m = fmaxf(m, lrelu(as1[(size_t)csr_src[j] * NHEADS + head] + ad));
  for (int off = 32; off; off >>= 1) m = fmaxf(m, __shfl_xor(m, off));
  float acc0 = 0.f, acc1 = 0.f, denom = 0.f;
  for (int j = lo; j < hi; ++j) {
    int s = csr_src[j];
    float w = __expf(lrelu(as1[(size_t)s * NHEADS + head] + ad) - m);
    ushort2 uv = *(const ushort2*)(h1b + (size_t)s * HID1 + head * CH1 + 2 * lane);
    acc0 += w * b2f(uv.x); acc1 += w * b2f(uv.y); denom += w;
  }
  { // self loop
    float w = __expf(e_self - m);
    ushort2 uv = *(const ushort2*)(h1b + (size_t)node * HID1 + head * CH1 + 2 * lane);
    acc0 += w * b2f(uv.x); acc1 += w * b2f(uv.y); denom += w;
  }
  float inv = 1.f / (denom + 1e-16f);
  float v0 = acc0 * inv + bias[head * CH1 + 2 * lane];
  float v1 = acc1 * inv + bias[head * CH1 + 2 * lane + 1];
  v0 = v0 > 0.f ? v0 : expm1f(v0);  // ELU
  v1 = v1 > 0.f ? v1 : expm1f(v1);
  ushort2 ov; ov.x = f2b(v0); ov.y = f2b(v1);
  *(ushort2*)(h2b + (size_t)node * HID1 + head * CH1 + 2 * lane) = ov;
}

// ---- layer-2 softmax + aggregate + bias -> fp32 out -----------------------
__global__ void aggregate2_kernel(const unsigned short* __restrict__ t2b,
                                  const float* __restrict__ as2,
                                  const float* __restrict__ ad2,
                                  const int* __restrict__ offsets,
                                  const int* __restrict__ csr_src,
                                  const float* __restrict__ bias,
                                  float* __restrict__ out, int n_nodes) {
  int node = blockIdx.x * 4 + (threadIdx.x >> 6);
  int lane = threadIdx.x & 63;
  if (node >= n_nodes) return;
  int lo = offsets[node], hi = offsets[node + 1];
  float ad = ad2[node];
  float e_self = lrelu(as2[node] + ad);
  float m = e_self;
  for (int j = lo + lane; j < hi; j += 64)
    m = fmaxf(m, lrelu(as2[csr_src[j]] + ad));
  for (int off = 32; off; off >>= 1) m = fmaxf(m, __shfl_xor(m, off));
  float acc0 = 0.f, acc1 = 0.f, denom = 0.f;
  for (int j = lo; j < hi; ++j) {
    int s = csr_src[j];
    float w = __expf(lrelu(as2[s] + ad) - m);
    ushort2 uv = *(const ushort2*)(t2b + (size_t)s * DOUT + 2 * lane);
    acc0 += w * b2f(uv.x); acc1 += w * b2f(uv.y); denom += w;
  }
  {
    float w = __expf(e_self - m);
    ushort2 uv = *(const ushort2*)(t2b + (size_t)node * DOUT + 2 * lane);
    acc0 += w * b2f(uv.x); acc1 += w * b2f(uv.y); denom += w;
  }
  float inv = 1.f / (denom + 1e-16f);
  out[(size_t)node * DOUT + 2 * lane]     = acc0 * inv + bias[2 * lane];
  out[(size_t)node * DOUT + 2 * lane + 1] = acc1 * inv + bias[2 * lane + 1];
}

extern "C" void kernel_launch(void* const* d_in, const int* in_sizes, int n_in,
                              void* d_out, int out_size, void* d_ws, size_t ws_size,
                              hipStream_t stream) {
  const float* x     = (const float*)d_in[0];
  const int* ei      = (const int*)d_in[1];
  const int* etype   = (const int*)d_in[2];
  const float* rel   = (const float*)d_in[3];
  const float* W1    = (const float*)d_in[4];
  const float* at_s1 = (const float*)d_in[5];
  const float* at_d1 = (const float*)d_in[6];
  const float* b1    = (const float*)d_in[7];
  const float* W2    = (const float*)d_in[8];
  const float* at_s2 = (const float*)d_in[9];
  const float* at_d2 = (const float*)d_in[10];
  const float* b2v   = (const float*)d_in[11];
  float* out         = (float*)d_out;

  const int N = in_sizes[0] / D_IN;  // 20000
  const int E = in_sizes[2];         // 640000
  const int* srcv = ei;
  const int* dstv = ei + E;

  char* p = (char*)d_ws;
  auto carve = [&](size_t bytes) -> char* {
    char* r = p; p += (bytes + 255) & ~(size_t)255; return r;
  };
  int*   counts  = (int*)carve((size_t)N * NREL * 4);
  int*   deg     = (int*)carve((size_t)N * 4);
  int*   offsets = (int*)carve(((size_t)N + 1) * 4);
  int*   cursor  = (int*)carve((size_t)N * 4);
  int*   bsum    = (int*)carve(64 * 4);
  int*   csr_src = (int*)carve((size_t)E * 4);
  float* as1     = (float*)carve((size_t)N * NHEADS * 4);
  float* ad1     = (float*)carve((size_t)N * NHEADS * 4);
  float* as2     = (float*)carve((size_t)N * 4);
  float* ad2     = (float*)carve((size_t)N * 4);
  unsigned short* W1T   = (unsigned short*)carve((size_t)HID1 * D_IN * 2);
  unsigned short* W2T   = (unsigned short*)carve((size_t)DOUT * HID1 * 2);
  unsigned short* x_modb = (unsigned short*)carve((size_t)M_PAD * D_IN * 2);
  unsigned short* h1b    = (unsigned short*)carve((size_t)M_PAD * HID1 * 2);
  unsigned short* h2b    = (unsigned short*)carve((size_t)M_PAD * HID1 * 2);
  unsigned short* t2b    = (unsigned short*)carve((size_t)M_PAD * DOUT * 2);

  hipMemsetAsync(counts, 0, (size_t)N * NREL * 4, stream);
  hipMemsetAsync(deg, 0, (size_t)N * 4, stream);
  hipMemsetAsync(cursor, 0, (size_t)N * 4, stream);

  int eb = (E + 255) / 256;
  int nb = (N + 1023) / 1024;  // 20
  count_kernel<<<eb, 256, 0, stream>>>(srcv, dstv, etype, counts, deg, E);
  scan_local<<<nb, 256, 0, stream>>>(deg, offsets, bsum, N);
  scan_blocks<<<1, 64, 0, stream>>>(bsum, nb, offsets, N);
  scan_add<<<nb, 256, 0, stream>>>(offsets, bsum, N);
  scatter_kernel<<<eb, 256, 0, stream>>>(srcv, dstv, offsets, cursor, csr_src, E);
  castT_kernel<<<(D_IN * HID1 + 255) / 256, 256, 0, stream>>>(W1, W1T, D_IN, HID1);
  castT_kernel<<<(HID1 * DOUT + 255) / 256, 256, 0, stream>>>(W2, W2T, HID1, DOUT);
  xmod_kernel<<<N, 256, 0, stream>>>(x, counts, rel, x_modb, N);
  mfma_gemm<<<dim3(HID1 / 128, M_PAD / 128), 256, 0, stream>>>(x_modb, W1T, h1b, N, HID1, D_IN);
  alpha1_kernel<<<N, 256, 0, stream>>>(h1b, at_s1, at_d1, as1, ad1, N);
  aggregate1_kernel<<<N, 256, 0, stream>>>(h1b, as1, ad1, offsets, csr_src, b1, h2b, N);
  mfma_gemm<<<dim3(DOUT / 128, M_PAD / 128), 256, 0, stream>>>(h2b, W2T, t2b, N, DOUT, HID1);
  alpha2_kernel<<<(N + 3) / 4, 256, 0, stream>>>(t2b, at_s2, at_d2, as2, ad2, N);
  aggregate2_kernel<<<(N + 3) / 4, 256, 0, stream>>>(t2b, as2, ad2, offsets, csr_src, b2v, out, N);
}

// Round 4
// 446.218 us; speedup vs baseline: 1.4989x; 1.1390x over previous
//
#include <hip/hip_runtime.h>

// N=20000, E=640000, D_IN=256, HID1=512 (4 heads x 128), D_OUT=128, R=32.
// fp32 inputs/outputs; internal h1/h2/t2/x_mod bf16 (gather traffic + MFMA).

#define D_IN   256
#define HID1   512
#define NHEADS 4
#define CH1    128
#define DOUT   128
#define NREL   32
#define NEG_SLOPE 0.2f
#define M_PAD  20096   // 157*128 == 314*64

static __device__ __forceinline__ float b2f(unsigned short u) {
  union { unsigned int i; float f; } v; v.i = ((unsigned int)u) << 16; return v.f;
}
static __device__ __forceinline__ unsigned short f2b(float f) {
  union { float f; unsigned int i; } v; v.f = f;
  unsigned int x = v.i;
  return (unsigned short)((x + 0x7fffu + ((x >> 16) & 1u)) >> 16);
}
static __device__ __forceinline__ float lrelu(float x) {
  return x > 0.f ? x : NEG_SLOPE * x;
}

typedef __attribute__((ext_vector_type(8))) short bf16x8;
typedef __attribute__((ext_vector_type(4))) float f32x4;

// ---- degree / relation counting ------------------------------------------
__global__ void count_kernel(const int* __restrict__ src, const int* __restrict__ dst,
                             const int* __restrict__ et, int* __restrict__ counts,
                             int* __restrict__ deg, int E) {
  int e = blockIdx.x * 256 + threadIdx.x;
  if (e >= E) return;
  atomicAdd(&counts[(size_t)src[e] * NREL + et[e]], 1);
  atomicAdd(&deg[dst[e]], 1);
}

// ---- hierarchical exclusive scan ------------------------------------------
__global__ void scan_local(const int* __restrict__ in, int* __restrict__ out,
                           int* __restrict__ bsum, int n) {
  __shared__ int wsum[4];
  int t = threadIdx.x;
  int base = blockIdx.x * 1024 + t * 4;
  int v0 = (base + 0 < n) ? in[base + 0] : 0;
  int v1 = (base + 1 < n) ? in[base + 1] : 0;
  int v2 = (base + 2 < n) ? in[base + 2] : 0;
  int v3 = (base + 3 < n) ? in[base + 3] : 0;
  int s = v0 + v1 + v2 + v3;
  int lane = t & 63, w = t >> 6;
  int sc = s;
  for (int off = 1; off < 64; off <<= 1) {
    int u = __shfl_up(sc, off);
    if (lane >= off) sc += u;
  }
  if (lane == 63) wsum[w] = sc;
  __syncthreads();
  int woff = 0;
  for (int i = 0; i < w; ++i) woff += wsum[i];
  int excl = woff + sc - s;
  if (base + 0 < n) out[base + 0] = excl;
  if (base + 1 < n) out[base + 1] = excl + v0;
  if (base + 2 < n) out[base + 2] = excl + v0 + v1;
  if (base + 3 < n) out[base + 3] = excl + v0 + v1 + v2;
  if (t == 255) bsum[blockIdx.x] = woff + sc;
}

__global__ void scan_blocks(int* __restrict__ bsum, int nb,
                            int* __restrict__ offsets, int n) {
  int t = threadIdx.x;  // 64
  int v = (t < nb) ? bsum[t] : 0;
  int sc = v;
  for (int off = 1; off < 64; off <<= 1) {
    int u = __shfl_up(sc, off);
    if (t >= off) sc += u;
  }
  if (t < nb) bsum[t] = sc - v;
  if (t == 63) offsets[n] = sc;
}

__global__ void scan_add(int* __restrict__ out, const int* __restrict__ bsum, int n) {
  int add = bsum[blockIdx.x];
  int i = blockIdx.x * 1024 + threadIdx.x * 4;
#pragma unroll
  for (int j = 0; j < 4; ++j)
    if (i + j < n) out[i + j] += add;
}

__global__ void scatter_kernel(const int* __restrict__ src, const int* __restrict__ dst,
                               const int* __restrict__ offsets, int* __restrict__ cursor,
                               int* __restrict__ csr_src, int E) {
  int e = blockIdx.x * 256 + threadIdx.x;
  if (e >= E) return;
  int d = dst[e];
  int pos = offsets[d] + atomicAdd(&cursor[d], 1);
  csr_src[pos] = src[e];
}

// ---- weight cast + transpose ---------------------------------------------
__global__ void castT_kernel(const float* __restrict__ W, unsigned short* __restrict__ WT,
                             int R, int C) {
  int idx = blockIdx.x * 256 + threadIdx.x;
  if (idx >= R * C) return;
  int r = idx / C, c = idx % C;
  WT[(size_t)c * R + r] = f2b(W[idx]);
}

// ---- x_mod ----------------------------------------------------------------
__global__ void xmod_kernel(const float* __restrict__ x,
                            const int* __restrict__ counts,
                            const float* __restrict__ rel,
                            unsigned short* __restrict__ x_modb, int n_nodes) {
  __shared__ int cnt[NREL];
  int node = blockIdx.x;
  if (threadIdx.x < NREL) cnt[threadIdx.x] = counts[(size_t)node * NREL + threadIdx.x];
  __syncthreads();
  int k = threadIdx.x;
  float v = x[(size_t)node * D_IN + k];
  for (int r = 0; r < NREL; ++r) {
    int c = cnt[r];
    if (c) v += (float)c * rel[r * D_IN + k];
  }
  x_modb[(size_t)node * D_IN + k] = f2b(v);
}

// ---- bf16 MFMA GEMM, templated block-M ------------------------------------
#define LDSW 40
template <int BM>
__global__ __launch_bounds__(256) void mfma_gemm(
    const unsigned short* __restrict__ A, const unsigned short* __restrict__ BT,
    unsigned short* __restrict__ C, int M, int N, int K) {
  constexpr int MFR = BM / 32;  // m-frags per wave
  __shared__ __align__(16) unsigned short Asl[BM * LDSW];
  __shared__ __align__(16) unsigned short Bsl[128 * LDSW];
  int tid = threadIdx.x;
  int m0 = blockIdx.y * BM, n0 = blockIdx.x * 128;
  int lane = tid & 63, wid = tid >> 6;
  int wm = wid & 1, wn = wid >> 1;
  int l16 = lane & 15, quad = lane >> 4;

  f32x4 acc[MFR][4];
#pragma unroll
  for (int i = 0; i < MFR; ++i)
#pragma unroll
    for (int j = 0; j < 4; ++j) acc[i][j] = (f32x4)(0.f);

  for (int k0 = 0; k0 < K; k0 += 32) {
#pragma unroll
    for (int lin = tid; lin < BM * 4; lin += 256) {
      int r = lin >> 2, seg = lin & 3;
      int gr = m0 + r; gr = gr < M ? gr : M - 1;
      *(uint4*)(&Asl[r * LDSW + seg * 8]) = *(const uint4*)(A + (size_t)gr * K + k0 + seg * 8);
    }
#pragma unroll
    for (int lin = tid; lin < 512; lin += 256) {
      int r = lin >> 2, seg = lin & 3;
      *(uint4*)(&Bsl[r * LDSW + seg * 8]) = *(const uint4*)(BT + (size_t)(n0 + r) * K + k0 + seg * 8);
    }
    __syncthreads();
    bf16x8 af[MFR], bfr[4];
#pragma unroll
    for (int mf = 0; mf < MFR; ++mf)
      af[mf] = *(const bf16x8*)(&Asl[(wm * (BM / 2) + mf * 16 + l16) * LDSW + quad * 8]);
#pragma unroll
    for (int nf = 0; nf < 4; ++nf)
      bfr[nf] = *(const bf16x8*)(&Bsl[(wn * 64 + nf * 16 + l16) * LDSW + quad * 8]);
#pragma unroll
    for (int mf = 0; mf < MFR; ++mf)
#pragma unroll
      for (int nf = 0; nf < 4; ++nf)
        acc[mf][nf] = __builtin_amdgcn_mfma_f32_16x16x32_bf16(af[mf], bfr[nf], acc[mf][nf], 0, 0, 0);
    __syncthreads();
  }
#pragma unroll
  for (int mf = 0; mf < MFR; ++mf)
#pragma unroll
    for (int nf = 0; nf < 4; ++nf)
#pragma unroll
      for (int r = 0; r < 4; ++r) {
        int row = m0 + wm * (BM / 2) + mf * 16 + quad * 4 + r;
        int col = n0 + wn * 64 + nf * 16 + l16;
        C[(size_t)row * N + col] = f2b(acc[mf][nf][r]);
      }
}

// ---- attention logits -----------------------------------------------------
__global__ void alpha1_kernel(const unsigned short* __restrict__ h1b,
                              const float* __restrict__ att_s,
                              const float* __restrict__ att_d,
                              float* __restrict__ as1, float* __restrict__ ad1,
                              int n_nodes) {
  int node = blockIdx.x;
  int head = threadIdx.x >> 6, lane = threadIdx.x & 63;
  ushort2 uv = *(const ushort2*)(h1b + (size_t)node * HID1 + head * CH1 + 2 * lane);
  float v0 = b2f(uv.x), v1 = b2f(uv.y);
  float s = v0 * att_s[head * CH1 + 2 * lane] + v1 * att_s[head * CH1 + 2 * lane + 1];
  float d = v0 * att_d[head * CH1 + 2 * lane] + v1 * att_d[head * CH1 + 2 * lane + 1];
  for (int off = 32; off; off >>= 1) { s += __shfl_xor(s, off); d += __shfl_xor(d, off); }
  if (lane == 0) { as1[(size_t)node * NHEADS + head] = s; ad1[(size_t)node * NHEADS + head] = d; }
}

__global__ void alpha2_kernel(const unsigned short* __restrict__ t2b,
                              const float* __restrict__ att_s,
                              const float* __restrict__ att_d,
                              float* __restrict__ as2, float* __restrict__ ad2,
                              int n_nodes) {
  int node = blockIdx.x * 4 + (threadIdx.x >> 6);
  int lane = threadIdx.x & 63;
  if (node >= n_nodes) return;
  ushort2 uv = *(const ushort2*)(t2b + (size_t)node * DOUT + 2 * lane);
  float v0 = b2f(uv.x), v1 = b2f(uv.y);
  float s = v0 * att_s[2 * lane] + v1 * att_s[2 * lane + 1];
  float d = v0 * att_d[2 * lane] + v1 * att_d[2 * lane + 1];
  for (int off = 32; off; off >>= 1) { s += __shfl_xor(s, off); d += __shfl_xor(d, off); }
  if (lane == 0) { as2[node] = s; ad2[node] = d; }
}

// ---- layer-1 aggregate: ONE WAVE PER NODE, 16B/lane -----------------------
// lane covers ch [8*lane .. 8*lane+7] of the 512-ch row; head = lane>>4
__global__ __launch_bounds__(256) void aggregate1_kernel(
    const unsigned short* __restrict__ h1b,
    const float* __restrict__ as1, const float* __restrict__ ad1,
    const int* __restrict__ offsets, const int* __restrict__ csr_src,
    const float* __restrict__ bias, unsigned short* __restrict__ h2b, int n_nodes) {
  int node = blockIdx.x * 4 + (threadIdx.x >> 6);
  if (node >= n_nodes) return;
  int lane = threadIdx.x & 63;
  int head = lane >> 4;
  int lo = offsets[node], hi = offsets[node + 1];
  const float4* as1v = (const float4*)as1;
  float4 asn = as1v[node];
  float4 ad4 = ((const float4*)ad1)[node];
  // per-head max (each lane tracks all 4 heads over its edge subset)
  float m0 = lrelu(asn.x + ad4.x), m1 = lrelu(asn.y + ad4.y);
  float m2 = lrelu(asn.z + ad4.z), m3 = lrelu(asn.w + ad4.w);
  for (int j = lo + lane; j < hi; j += 64) {
    float4 a = as1v[csr_src[j]];
    m0 = fmaxf(m0, lrelu(a.x + ad4.x)); m1 = fmaxf(m1, lrelu(a.y + ad4.y));
    m2 = fmaxf(m2, lrelu(a.z + ad4.z)); m3 = fmaxf(m3, lrelu(a.w + ad4.w));
  }
  for (int off = 32; off; off >>= 1) {
    m0 = fmaxf(m0, __shfl_xor(m0, off)); m1 = fmaxf(m1, __shfl_xor(m1, off));
    m2 = fmaxf(m2, __shfl_xor(m2, off)); m3 = fmaxf(m3, __shfl_xor(m3, off));
  }
  float m_own  = head == 0 ? m0 : head == 1 ? m1 : head == 2 ? m2 : m3;
  float ad_own = head == 0 ? ad4.x : head == 1 ? ad4.y : head == 2 ? ad4.z : ad4.w;
  float as_own = head == 0 ? asn.x : head == 1 ? asn.y : head == 2 ? asn.z : asn.w;

  const uint4* h1v = (const uint4*)h1b;
  float acc[8] = {0.f, 0.f, 0.f, 0.f, 0.f, 0.f, 0.f, 0.f};
  float denom = 0.f;
  int sj = (lo < hi) ? csr_src[lo] : node;
  for (int j = lo; j < hi; ++j) {
    int snext = (j + 1 < hi) ? csr_src[j + 1] : node;
    float asv = as1[sj * 4 + head];
    uint4 hv = h1v[(size_t)sj * 64 + lane];
    float w = __expf(lrelu(asv + ad_own) - m_own);
    unsigned int u;
    union { unsigned int i; float f; } cl, ch;
    u = hv.x; cl.i = u << 16; ch.i = u & 0xffff0000u; acc[0] += w * cl.f; acc[1] += w * ch.f;
    u = hv.y; cl.i = u << 16; ch.i = u & 0xffff0000u; acc[2] += w * cl.f; acc[3] += w * ch.f;
    u = hv.z; cl.i = u << 16; ch.i = u & 0xffff0000u; acc[4] += w * cl.f; acc[5] += w * ch.f;
    u = hv.w; cl.i = u << 16; ch.i = u & 0xffff0000u; acc[6] += w * cl.f; acc[7] += w * ch.f;
    denom += w;
    sj = snext;
  }
  { // self loop
    uint4 hv = h1v[(size_t)node * 64 + lane];
    float w = __expf(lrelu(as_own + ad_own) - m_own);
    unsigned int u;
    union { unsigned int i; float f; } cl, ch;
    u = hv.x; cl.i = u << 16; ch.i = u & 0xffff0000u; acc[0] += w * cl.f; acc[1] += w * ch.f;
    u = hv.y; cl.i = u << 16; ch.i = u & 0xffff0000u; acc[2] += w * cl.f; acc[3] += w * ch.f;
    u = hv.z; cl.i = u << 16; ch.i = u & 0xffff0000u; acc[4] += w * cl.f; acc[5] += w * ch.f;
    u = hv.w; cl.i = u << 16; ch.i = u & 0xffff0000u; acc[6] += w * cl.f; acc[7] += w * ch.f;
    denom += w;
  }
  float inv = 1.f / (denom + 1e-16f);
  uint4 ov;
  unsigned int od[4];
#pragma unroll
  for (int q = 0; q < 4; ++q) {
    float vlo = acc[2 * q] * inv + bias[lane * 8 + 2 * q];
    float vhi = acc[2 * q + 1] * inv + bias[lane * 8 + 2 * q + 1];
    vlo = vlo > 0.f ? vlo : expm1f(vlo);
    vhi = vhi > 0.f ? vhi : expm1f(vhi);
    od[q] = (unsigned int)f2b(vlo) | ((unsigned int)f2b(vhi) << 16);
  }
  ov.x = od[0]; ov.y = od[1]; ov.z = od[2]; ov.w = od[3];
  ((uint4*)h2b)[(size_t)node * 64 + lane] = ov;
}

// ---- layer-2 aggregate: one wave per node, 2 edges/iter (half-wave each) --
__global__ __launch_bounds__(256) void aggregate2_kernel(
    const unsigned short* __restrict__ t2b,
    const float* __restrict__ as2, const float* __restrict__ ad2,
    const int* __restrict__ offsets, const int* __restrict__ csr_src,
    const float* __restrict__ bias, float* __restrict__ out, int n_nodes) {
  int node = blockIdx.x * 4 + (threadIdx.x >> 6);
  if (node >= n_nodes) return;
  int lane = threadIdx.x & 63;
  int half = lane >> 5, l32 = lane & 31;  // lane covers ch [4*l32..4*l32+3]
  int lo = offsets[node], hi = offsets[node + 1];
  float ad = ad2[node];
  float e_self = lrelu(as2[node] + ad);
  float m = e_self;
  for (int j = lo + lane; j < hi; j += 64)
    m = fmaxf(m, lrelu(as2[csr_src[j]] + ad));
  for (int off = 32; off; off >>= 1) m = fmaxf(m, __shfl_xor(m, off));

  const uint2* t2v = (const uint2*)t2b;  // 32 uint2 per 256B row
  float acc[4] = {0.f, 0.f, 0.f, 0.f};
  float denom = 0.f;
  int cnt = hi - lo;
  int nit = (cnt + 1) >> 1;
  for (int i = 0; i < nit; ++i) {
    int j = lo + 2 * i + half;
    bool valid = j < hi;
    int s = valid ? csr_src[j] : node;
    uint2 tv = t2v[(size_t)s * 32 + l32];
    float w = valid ? __expf(lrelu(as2[s] + ad) - m) : 0.f;
    unsigned int u;
    union { unsigned int i; float f; } cl, ch;
    u = tv.x; cl.i = u << 16; ch.i = u & 0xffff0000u; acc[0] += w * cl.f; acc[1] += w * ch.f;
    u = tv.y; cl.i = u << 16; ch.i = u & 0xffff0000u; acc[2] += w * cl.f; acc[3] += w * ch.f;
    denom += w;
  }
  if (half == 0) {  // self loop on lower half
    uint2 tv = t2v[(size_t)node * 32 + l32];
    float w = __expf(e_self - m);
    unsigned int u;
    union { unsigned int i; float f; } cl, ch;
    u = tv.x; cl.i = u << 16; ch.i = u & 0xffff0000u; acc[0] += w * cl.f; acc[1] += w * ch.f;
    u = tv.y; cl.i = u << 16; ch.i = u & 0xffff0000u; acc[2] += w * cl.f; acc[3] += w * ch.f;
    denom += w;
  }
#pragma unroll
  for (int k = 0; k < 4; ++k) acc[k] += __shfl_xor(acc[k], 32);
  denom += __shfl_xor(denom, 32);
  if (half == 0) {
    float inv = 1.f / (denom + 1e-16f);
    float4 o;
    o.x = acc[0] * inv + bias[l32 * 4 + 0];
    o.y = acc[1] * inv + bias[l32 * 4 + 1];
    o.z = acc[2] * inv + bias[l32 * 4 + 2];
    o.w = acc[3] * inv + bias[l32 * 4 + 3];
    *(float4*)(out + (size_t)node * DOUT + l32 * 4) = o;
  }
}

extern "C" void kernel_launch(void* const* d_in, const int* in_sizes, int n_in,
                              void* d_out, int out_size, void* d_ws, size_t ws_size,
                              hipStream_t stream) {
  const float* x     = (const float*)d_in[0];
  const int* ei      = (const int*)d_in[1];
  const int* etype   = (const int*)d_in[2];
  const float* rel   = (const float*)d_in[3];
  const float* W1    = (const float*)d_in[4];
  const float* at_s1 = (const float*)d_in[5];
  const float* at_d1 = (const float*)d_in[6];
  const float* b1    = (const float*)d_in[7];
  const float* W2    = (const float*)d_in[8];
  const float* at_s2 = (const float*)d_in[9];
  const float* at_d2 = (const float*)d_in[10];
  const float* b2v   = (const float*)d_in[11];
  float* out         = (float*)d_out;

  const int N = in_sizes[0] / D_IN;  // 20000
  const int E = in_sizes[2];         // 640000
  const int* srcv = ei;
  const int* dstv = ei + E;

  char* p = (char*)d_ws;
  auto carve = [&](size_t bytes) -> char* {
    char* r = p; p += (bytes + 255) & ~(size_t)255; return r;
  };
  int*   counts  = (int*)carve((size_t)N * NREL * 4);
  int*   deg     = (int*)carve((size_t)N * 4);
  int*   offsets = (int*)carve(((size_t)N + 1) * 4);
  int*   cursor  = (int*)carve((size_t)N * 4);
  int*   bsum    = (int*)carve(64 * 4);
  int*   csr_src = (int*)carve((size_t)E * 4);
  float* as1     = (float*)carve((size_t)N * NHEADS * 4);
  float* ad1     = (float*)carve((size_t)N * NHEADS * 4);
  float* as2     = (float*)carve((size_t)N * 4);
  float* ad2     = (float*)carve((size_t)N * 4);
  unsigned short* W1T    = (unsigned short*)carve((size_t)HID1 * D_IN * 2);
  unsigned short* W2T    = (unsigned short*)carve((size_t)DOUT * HID1 * 2);
  unsigned short* x_modb = (unsigned short*)carve((size_t)M_PAD * D_IN * 2);
  unsigned short* h1b    = (unsigned short*)carve((size_t)M_PAD * HID1 * 2);
  unsigned short* h2b    = (unsigned short*)carve((size_t)M_PAD * HID1 * 2);
  unsigned short* t2b    = (unsigned short*)carve((size_t)M_PAD * DOUT * 2);

  hipMemsetAsync(counts, 0, (size_t)N * NREL * 4, stream);
  hipMemsetAsync(deg, 0, (size_t)N * 4, stream);
  hipMemsetAsync(cursor, 0, (size_t)N * 4, stream);

  int eb = (E + 255) / 256;
  int nb = (N + 1023) / 1024;  // 20
  count_kernel<<<eb, 256, 0, stream>>>(srcv, dstv, etype, counts, deg, E);
  scan_local<<<nb, 256, 0, stream>>>(deg, offsets, bsum, N);
  scan_blocks<<<1, 64, 0, stream>>>(bsum, nb, offsets, N);
  scan_add<<<nb, 256, 0, stream>>>(offsets, bsum, N);
  scatter_kernel<<<eb, 256, 0, stream>>>(srcv, dstv, offsets, cursor, csr_src, E);
  castT_kernel<<<(D_IN * HID1 + 255) / 256, 256, 0, stream>>>(W1, W1T, D_IN, HID1);
  castT_kernel<<<(HID1 * DOUT + 255) / 256, 256, 0, stream>>>(W2, W2T, HID1, DOUT);
  xmod_kernel<<<N, 256, 0, stream>>>(x, counts, rel, x_modb, N);
  mfma_gemm<128><<<dim3(HID1 / 128, M_PAD / 128), 256, 0, stream>>>(x_modb, W1T, h1b, N, HID1, D_IN);
  alpha1_kernel<<<N, 256, 0, stream>>>(h1b, at_s1, at_d1, as1, ad1, N);
  aggregate1_kernel<<<(N + 3) / 4, 256, 0, stream>>>(h1b, as1, ad1, offsets, csr_src, b1, h2b, N);
  mfma_gemm<64><<<dim3(DOUT / 128, M_PAD / 64), 256, 0, stream>>>(h2b, W2T, t2b, N, DOUT, HID1);
  alpha2_kernel<<<(N + 3) / 4, 256, 0, stream>>>(t2b, at_s2, at_d2, as2, ad2, N);
  aggregate2_kernel<<<(N + 3) / 4, 256, 0, stream>>>(t2b, as2, ad2, offsets, csr_src, b2v, out, N);
}

// Round 5
// 388.473 us; speedup vs baseline: 1.7217x; 1.1486x over previous
//
#include <hip/hip_runtime.h>

// N=20000, E=640000, D_IN=256, HID1=512 (4 heads x 128), D_OUT=128, R=32.
// fp32 inputs/outputs; internal h1/h2/t2/x_mod bf16 (gather traffic + MFMA).

#define D_IN   256
#define HID1   512
#define NHEADS 4
#define CH1    128
#define DOUT   128
#define NREL   32
#define NEG_SLOPE 0.2f
#define M_PAD  20096   // 157*128 == 314*64

static __device__ __forceinline__ float b2f(unsigned short u) {
  union { unsigned int i; float f; } v; v.i = ((unsigned int)u) << 16; return v.f;
}
static __device__ __forceinline__ unsigned short f2b(float f) {
  union { float f; unsigned int i; } v; v.f = f;
  unsigned int x = v.i;
  return (unsigned short)((x + 0x7fffu + ((x >> 16) & 1u)) >> 16);
}
static __device__ __forceinline__ float lrelu(float x) {
  return x > 0.f ? x : NEG_SLOPE * x;
}

typedef __attribute__((ext_vector_type(8))) short bf16x8;
typedef __attribute__((ext_vector_type(4))) float f32x4;

// ---- degree / relation counting ------------------------------------------
__global__ void count_kernel(const int* __restrict__ src, const int* __restrict__ dst,
                             const int* __restrict__ et, int* __restrict__ counts,
                             int* __restrict__ deg, int E) {
  int e = blockIdx.x * 256 + threadIdx.x;
  if (e >= E) return;
  atomicAdd(&counts[(size_t)src[e] * NREL + et[e]], 1);
  atomicAdd(&deg[dst[e]], 1);
}

// ---- hierarchical exclusive scan ------------------------------------------
__global__ void scan_local(const int* __restrict__ in, int* __restrict__ out,
                           int* __restrict__ bsum, int n) {
  __shared__ int wsum[4];
  int t = threadIdx.x;
  int base = blockIdx.x * 1024 + t * 4;
  int v0 = (base + 0 < n) ? in[base + 0] : 0;
  int v1 = (base + 1 < n) ? in[base + 1] : 0;
  int v2 = (base + 2 < n) ? in[base + 2] : 0;
  int v3 = (base + 3 < n) ? in[base + 3] : 0;
  int s = v0 + v1 + v2 + v3;
  int lane = t & 63, w = t >> 6;
  int sc = s;
  for (int off = 1; off < 64; off <<= 1) {
    int u = __shfl_up(sc, off);
    if (lane >= off) sc += u;
  }
  if (lane == 63) wsum[w] = sc;
  __syncthreads();
  int woff = 0;
  for (int i = 0; i < w; ++i) woff += wsum[i];
  int excl = woff + sc - s;
  if (base + 0 < n) out[base + 0] = excl;
  if (base + 1 < n) out[base + 1] = excl + v0;
  if (base + 2 < n) out[base + 2] = excl + v0 + v1;
  if (base + 3 < n) out[base + 3] = excl + v0 + v1 + v2;
  if (t == 255) bsum[blockIdx.x] = woff + sc;
}

__global__ void scan_blocks(int* __restrict__ bsum, int nb,
                            int* __restrict__ offsets, int n) {
  int t = threadIdx.x;  // 64
  int v = (t < nb) ? bsum[t] : 0;
  int sc = v;
  for (int off = 1; off < 64; off <<= 1) {
    int u = __shfl_up(sc, off);
    if (t >= off) sc += u;
  }
  if (t < nb) bsum[t] = sc - v;
  if (t == 63) offsets[n] = sc;
}

__global__ void scan_add(int* __restrict__ out, const int* __restrict__ bsum, int n) {
  int add = bsum[blockIdx.x];
  int i = blockIdx.x * 1024 + threadIdx.x * 4;
#pragma unroll
  for (int j = 0; j < 4; ++j)
    if (i + j < n) out[i + j] += add;
}

__global__ void scatter_kernel(const int* __restrict__ src, const int* __restrict__ dst,
                               const int* __restrict__ offsets, int* __restrict__ cursor,
                               int* __restrict__ csr_src, int E) {
  int e = blockIdx.x * 256 + threadIdx.x;
  if (e >= E) return;
  int d = dst[e];
  int pos = offsets[d] + atomicAdd(&cursor[d], 1);
  csr_src[pos] = src[e];
}

// ---- weight cast + transpose (both weights, one launch) -------------------
__global__ void castT_both(const float* __restrict__ W1, const float* __restrict__ W2,
                           unsigned short* __restrict__ W1T, unsigned short* __restrict__ W2T) {
  int idx = blockIdx.x * 256 + threadIdx.x;
  if (idx < D_IN * HID1) {
    int r = idx / HID1, c = idx % HID1;
    W1T[(size_t)c * D_IN + r] = f2b(W1[idx]);
  } else {
    int k = idx - D_IN * HID1;
    if (k < HID1 * DOUT) {
      int r = k / DOUT, c = k % DOUT;
      W2T[(size_t)c * HID1 + r] = f2b(W2[k]);
    }
  }
}

// ---- x_mod ----------------------------------------------------------------
__global__ void xmod_kernel(const float* __restrict__ x,
                            const int* __restrict__ counts,
                            const float* __restrict__ rel,
                            unsigned short* __restrict__ x_modb, int n_nodes) {
  __shared__ int cnt[NREL];
  int node = blockIdx.x;
  if (threadIdx.x < NREL) cnt[threadIdx.x] = counts[(size_t)node * NREL + threadIdx.x];
  __syncthreads();
  int k = threadIdx.x;
  float v = x[(size_t)node * D_IN + k];
  for (int r = 0; r < NREL; ++r) {
    int c = cnt[r];
    if (c) v += (float)c * rel[r * D_IN + k];
  }
  x_modb[(size_t)node * D_IN + k] = f2b(v);
}

// ---- bf16 MFMA GEMM, global_load_lds staging, contiguous LDS --------------
// Row stride in LDS = 32 bf16 (64B). Wave-chunk = 16 rows = 1KB (lane*16B).
template <int BM>
__global__ __launch_bounds__(256) void mfma_gemm(
    const unsigned short* __restrict__ A, const unsigned short* __restrict__ BT,
    unsigned short* __restrict__ C, int M, int N, int K) {
  constexpr int MFR = BM / 32;  // m-frags per wave
  __shared__ __align__(16) unsigned short Asl[BM * 32];
  __shared__ __align__(16) unsigned short Bsl[128 * 32];
  int tid = threadIdx.x;
  int m0 = blockIdx.y * BM, n0 = blockIdx.x * 128;
  int lane = tid & 63, wv = tid >> 6;
  int wm = wv & 1, wn = wv >> 1;
  int l16 = lane & 15, quad = lane >> 4;
  int lr = lane >> 2, lseg = lane & 3;  // staging: row-in-chunk, 16B segment

  f32x4 acc[MFR][4];
#pragma unroll
  for (int i = 0; i < MFR; ++i)
#pragma unroll
    for (int j = 0; j < 4; ++j) acc[i][j] = (f32x4)(0.f);

  for (int k0 = 0; k0 < K; k0 += 32) {
#pragma unroll
    for (int c = wv; c < BM / 16; c += 4) {
      int gr = m0 + c * 16 + lr; gr = gr < M ? gr : M - 1;
      __builtin_amdgcn_global_load_lds(
          (const __attribute__((address_space(1))) void*)(A + (size_t)gr * K + k0 + lseg * 8),
          (__attribute__((address_space(3))) void*)(&Asl[c * 512]), 16, 0, 0);
    }
#pragma unroll
    for (int c = wv; c < 8; c += 4) {
      int gr = n0 + c * 16 + lr;
      __builtin_amdgcn_global_load_lds(
          (const __attribute__((address_space(1))) void*)(BT + (size_t)gr * K + k0 + lseg * 8),
          (__attribute__((address_space(3))) void*)(&Bsl[c * 512]), 16, 0, 0);
    }
    __syncthreads();
    bf16x8 af[MFR], bfr[4];
#pragma unroll
    for (int mf = 0; mf < MFR; ++mf)
      af[mf] = *(const bf16x8*)(&Asl[(wm * (BM / 2) + mf * 16 + l16) * 32 + quad * 8]);
#pragma unroll
    for (int nf = 0; nf < 4; ++nf)
      bfr[nf] = *(const bf16x8*)(&Bsl[(wn * 64 + nf * 16 + l16) * 32 + quad * 8]);
#pragma unroll
    for (int mf = 0; mf < MFR; ++mf)
#pragma unroll
      for (int nf = 0; nf < 4; ++nf)
        acc[mf][nf] = __builtin_amdgcn_mfma_f32_16x16x32_bf16(af[mf], bfr[nf], acc[mf][nf], 0, 0, 0);
    __syncthreads();
  }
#pragma unroll
  for (int mf = 0; mf < MFR; ++mf)
#pragma unroll
    for (int nf = 0; nf < 4; ++nf)
#pragma unroll
      for (int r = 0; r < 4; ++r) {
        int row = m0 + wm * (BM / 2) + mf * 16 + quad * 4 + r;
        int col = n0 + wn * 64 + nf * 16 + l16;
        C[(size_t)row * N + col] = f2b(acc[mf][nf][r]);
      }
}

// ---- attention logits -----------------------------------------------------
__global__ void alpha1_kernel(const unsigned short* __restrict__ h1b,
                              const float* __restrict__ att_s,
                              const float* __restrict__ att_d,
                              float* __restrict__ as1, float* __restrict__ ad1,
                              int n_nodes) {
  int node = blockIdx.x;
  int head = threadIdx.x >> 6, lane = threadIdx.x & 63;
  ushort2 uv = *(const ushort2*)(h1b + (size_t)node * HID1 + head * CH1 + 2 * lane);
  float v0 = b2f(uv.x), v1 = b2f(uv.y);
  float s = v0 * att_s[head * CH1 + 2 * lane] + v1 * att_s[head * CH1 + 2 * lane + 1];
  float d = v0 * att_d[head * CH1 + 2 * lane] + v1 * att_d[head * CH1 + 2 * lane + 1];
  for (int off = 32; off; off >>= 1) { s += __shfl_xor(s, off); d += __shfl_xor(d, off); }
  if (lane == 0) { as1[(size_t)node * NHEADS + head] = s; ad1[(size_t)node * NHEADS + head] = d; }
}

__global__ void alpha2_kernel(const unsigned short* __restrict__ t2b,
                              const float* __restrict__ att_s,
                              const float* __restrict__ att_d,
                              float* __restrict__ as2, float* __restrict__ ad2,
                              int n_nodes) {
  int node = blockIdx.x * 4 + (threadIdx.x >> 6);
  int lane = threadIdx.x & 63;
  if (node >= n_nodes) return;
  ushort2 uv = *(const ushort2*)(t2b + (size_t)node * DOUT + 2 * lane);
  float v0 = b2f(uv.x), v1 = b2f(uv.y);
  float s = v0 * att_s[2 * lane] + v1 * att_s[2 * lane + 1];
  float d = v0 * att_d[2 * lane] + v1 * att_d[2 * lane + 1];
  for (int off = 32; off; off >>= 1) { s += __shfl_xor(s, off); d += __shfl_xor(d, off); }
  if (lane == 0) { as2[node] = s; ad2[node] = d; }
}

// ---- layer-1 aggregate: one wave per node, 2 edges/iter -------------------
// group g=lane>>5 handles edge lo+2i+g; lane covers ch [16*l32..16*l32+15]
__global__ __launch_bounds__(256) void aggregate1_kernel(
    const unsigned short* __restrict__ h1b,
    const float* __restrict__ as1, const float* __restrict__ ad1,
    const int* __restrict__ offsets, const int* __restrict__ csr_src,
    const float* __restrict__ bias, unsigned short* __restrict__ h2b, int n_nodes) {
  int node = blockIdx.x * 4 + (threadIdx.x >> 6);
  if (node >= n_nodes) return;
  int lane = threadIdx.x & 63;
  int g = lane >> 5, l32 = lane & 31;
  int head = l32 >> 3;                      // 8 l32-lanes per head
  int lo = offsets[node], hi = offsets[node + 1];
  const float4* as1v = (const float4*)as1;
  float4 asn = as1v[node];
  float4 ad4 = ((const float4*)ad1)[node];
  float m0 = lrelu(asn.x + ad4.x), m1 = lrelu(asn.y + ad4.y);
  float m2 = lrelu(asn.z + ad4.z), m3 = lrelu(asn.w + ad4.w);
  for (int j = lo + lane; j < hi; j += 64) {
    float4 a = as1v[csr_src[j]];
    m0 = fmaxf(m0, lrelu(a.x + ad4.x)); m1 = fmaxf(m1, lrelu(a.y + ad4.y));
    m2 = fmaxf(m2, lrelu(a.z + ad4.z)); m3 = fmaxf(m3, lrelu(a.w + ad4.w));
  }
  for (int off = 32; off; off >>= 1) {
    m0 = fmaxf(m0, __shfl_xor(m0, off)); m1 = fmaxf(m1, __shfl_xor(m1, off));
    m2 = fmaxf(m2, __shfl_xor(m2, off)); m3 = fmaxf(m3, __shfl_xor(m3, off));
  }
  float m_own  = head == 0 ? m0 : head == 1 ? m1 : head == 2 ? m2 : m3;
  float ad_own = head == 0 ? ad4.x : head == 1 ? ad4.y : head == 2 ? ad4.z : ad4.w;
  float as_own = head == 0 ? asn.x : head == 1 ? asn.y : head == 2 ? asn.z : asn.w;

  const uint4* h1v = (const uint4*)h1b;  // 64 x 16B per row
  float acc[16];
#pragma unroll
  for (int k = 0; k < 16; ++k) acc[k] = 0.f;
  float denom = 0.f;

  int nit = (hi - lo + 1) >> 1;
  int j = lo + g;
  bool valid = j < hi;
  int s = valid ? csr_src[j] : node;
  float asv = as1[s * 4 + head];  // software-pipelined one iteration ahead
  for (int i = 0; i < nit; ++i) {
    int jn = j + 2;
    bool vn = jn < hi;
    int sn = vn ? csr_src[jn] : node;
    float asv_n = as1[sn * 4 + head];          // next as1 in flight
    uint4 h0 = h1v[(size_t)s * 64 + l32 * 2];  // 32B of current row
    uint4 h1r = h1v[(size_t)s * 64 + l32 * 2 + 1];
    float w = valid ? __expf(lrelu(asv + ad_own) - m_own) : 0.f;
    unsigned int u;
    union { unsigned int i; float f; } cl, ch;
    u = h0.x; cl.i = u << 16; ch.i = u & 0xffff0000u; acc[0] += w * cl.f; acc[1] += w * ch.f;
    u = h0.y; cl.i = u << 16; ch.i = u & 0xffff0000u; acc[2] += w * cl.f; acc[3] += w * ch.f;
    u = h0.z; cl.i = u << 16; ch.i = u & 0xffff0000u; acc[4] += w * cl.f; acc[5] += w * ch.f;
    u = h0.w; cl.i = u << 16; ch.i = u & 0xffff0000u; acc[6] += w * cl.f; acc[7] += w * ch.f;
    u = h1r.x; cl.i = u << 16; ch.i = u & 0xffff0000u; acc[8]  += w * cl.f; acc[9]  += w * ch.f;
    u = h1r.y; cl.i = u << 16; ch.i = u & 0xffff0000u; acc[10] += w * cl.f; acc[11] += w * ch.f;
    u = h1r.z; cl.i = u << 16; ch.i = u & 0xffff0000u; acc[12] += w * cl.f; acc[13] += w * ch.f;
    u = h1r.w; cl.i = u << 16; ch.i = u & 0xffff0000u; acc[14] += w * cl.f; acc[15] += w * ch.f;
    denom += w;
    j = jn; valid = vn; s = sn; asv = asv_n;
  }
  if (g == 0) {  // self loop, group 0 only
    uint4 h0 = h1v[(size_t)node * 64 + l32 * 2];
    uint4 h1r = h1v[(size_t)node * 64 + l32 * 2 + 1];
    float w = __expf(lrelu(as_own + ad_own) - m_own);
    unsigned int u;
    union { unsigned int i; float f; } cl, ch;
    u = h0.x; cl.i = u << 16; ch.i = u & 0xffff0000u; acc[0] += w * cl.f; acc[1] += w * ch.f;
    u = h0.y; cl.i = u << 16; ch.i = u & 0xffff0000u; acc[2] += w * cl.f; acc[3] += w * ch.f;
    u = h0.z; cl.i = u << 16; ch.i = u & 0xffff0000u; acc[4] += w * cl.f; acc[5] += w * ch.f;
    u = h0.w; cl.i = u << 16; ch.i = u & 0xffff0000u; acc[6] += w * cl.f; acc[7] += w * ch.f;
    u = h1r.x; cl.i = u << 16; ch.i = u & 0xffff0000u; acc[8]  += w * cl.f; acc[9]  += w * ch.f;
    u = h1r.y; cl.i = u << 16; ch.i = u & 0xffff0000u; acc[10] += w * cl.f; acc[11] += w * ch.f;
    u = h1r.z; cl.i = u << 16; ch.i = u & 0xffff0000u; acc[12] += w * cl.f; acc[13] += w * ch.f;
    u = h1r.w; cl.i = u << 16; ch.i = u & 0xffff0000u; acc[14] += w * cl.f; acc[15] += w * ch.f;
    denom += w;
  }
#pragma unroll
  for (int k = 0; k < 16; ++k) acc[k] += __shfl_xor(acc[k], 32);
  denom += __shfl_xor(denom, 32);
  if (g == 0) {
    float inv = 1.f / (denom + 1e-16f);
    unsigned int od[8];
#pragma unroll
    for (int q = 0; q < 8; ++q) {
      float vlo = acc[2 * q] * inv + bias[l32 * 16 + 2 * q];
      float vhi = acc[2 * q + 1] * inv + bias[l32 * 16 + 2 * q + 1];
      vlo = vlo > 0.f ? vlo : expm1f(vlo);
      vhi = vhi > 0.f ? vhi : expm1f(vhi);
      od[q] = (unsigned int)f2b(vlo) | ((unsigned int)f2b(vhi) << 16);
    }
    uint4 o0; o0.x = od[0]; o0.y = od[1]; o0.z = od[2]; o0.w = od[3];
    uint4 o1; o1.x = od[4]; o1.y = od[5]; o1.z = od[6]; o1.w = od[7];
    ((uint4*)h2b)[(size_t)node * 64 + l32 * 2] = o0;
    ((uint4*)h2b)[(size_t)node * 64 + l32 * 2 + 1] = o1;
  }
}

// ---- layer-2 aggregate: one wave per node, 4 edges/iter -------------------
// group g=lane>>4 handles edge lo+4i+g; lane covers ch [8*l16..8*l16+7]
__global__ __launch_bounds__(256) void aggregate2_kernel(
    const unsigned short* __restrict__ t2b,
    const float* __restrict__ as2, const float* __restrict__ ad2,
    const int* __restrict__ offsets, const int* __restrict__ csr_src,
    const float* __restrict__ bias, float* __restrict__ out, int n_nodes) {
  int node = blockIdx.x * 4 + (threadIdx.x >> 6);
  if (node >= n_nodes) return;
  int lane = threadIdx.x & 63;
  int g = lane >> 4, l16 = lane & 15;
  int lo = offsets[node], hi = offsets[node + 1];
  float ad = ad2[node];
  float e_self = lrelu(as2[node] + ad);
  float m = e_self;
  for (int j = lo + lane; j < hi; j += 64)
    m = fmaxf(m, lrelu(as2[csr_src[j]] + ad));
  for (int off = 32; off; off >>= 1) m = fmaxf(m, __shfl_xor(m, off));

  const uint4* t2v = (const uint4*)t2b;  // 16 x 16B per row
  float acc[8] = {0.f, 0.f, 0.f, 0.f, 0.f, 0.f, 0.f, 0.f};
  float denom = 0.f;
  int nit = (hi - lo + 3) >> 2;
  int j = lo + g;
  bool valid = j < hi;
  int s = valid ? csr_src[j] : node;
  float asv = as2[s];
  for (int i = 0; i < nit; ++i) {
    int jn = j + 4;
    bool vn = jn < hi;
    int sn = vn ? csr_src[jn] : node;
    float asv_n = as2[sn];
    uint4 tv = t2v[(size_t)s * 16 + l16];
    float w = valid ? __expf(lrelu(asv + ad) - m) : 0.f;
    unsigned int u;
    union { unsigned int i; float f; } cl, ch;
    u = tv.x; cl.i = u << 16; ch.i = u & 0xffff0000u; acc[0] += w * cl.f; acc[1] += w * ch.f;
    u = tv.y; cl.i = u << 16; ch.i = u & 0xffff0000u; acc[2] += w * cl.f; acc[3] += w * ch.f;
    u = tv.z; cl.i = u << 16; ch.i = u & 0xffff0000u; acc[4] += w * cl.f; acc[5] += w * ch.f;
    u = tv.w; cl.i = u << 16; ch.i = u & 0xffff0000u; acc[6] += w * cl.f; acc[7] += w * ch.f;
    denom += w;
    j = jn; valid = vn; s = sn; asv = asv_n;
  }
  if (g == 0) {  // self loop
    uint4 tv = t2v[(size_t)node * 16 + l16];
    float w = __expf(e_self - m);
    unsigned int u;
    union { unsigned int i; float f; } cl, ch;
    u = tv.x; cl.i = u << 16; ch.i = u & 0xffff0000u; acc[0] += w * cl.f; acc[1] += w * ch.f;
    u = tv.y; cl.i = u << 16; ch.i = u & 0xffff0000u; acc[2] += w * cl.f; acc[3] += w * ch.f;
    u = tv.z; cl.i = u << 16; ch.i = u & 0xffff0000u; acc[4] += w * cl.f; acc[5] += w * ch.f;
    u = tv.w; cl.i = u << 16; ch.i = u & 0xffff0000u; acc[6] += w * cl.f; acc[7] += w * ch.f;
    denom += w;
  }
#pragma unroll
  for (int k = 0; k < 8; ++k) {
    acc[k] += __shfl_xor(acc[k], 16);
    acc[k] += __shfl_xor(acc[k], 32);
  }
  denom += __shfl_xor(denom, 16);
  denom += __shfl_xor(denom, 32);
  if (g == 0) {
    float inv = 1.f / (denom + 1e-16f);
    float4 o0, o1;
    o0.x = acc[0] * inv + bias[l16 * 8 + 0];
    o0.y = acc[1] * inv + bias[l16 * 8 + 1];
    o0.z = acc[2] * inv + bias[l16 * 8 + 2];
    o0.w = acc[3] * inv + bias[l16 * 8 + 3];
    o1.x = acc[4] * inv + bias[l16 * 8 + 4];
    o1.y = acc[5] * inv + bias[l16 * 8 + 5];
    o1.z = acc[6] * inv + bias[l16 * 8 + 6];
    o1.w = acc[7] * inv + bias[l16 * 8 + 7];
    *(float4*)(out + (size_t)node * DOUT + l16 * 8) = o0;
    *(float4*)(out + (size_t)node * DOUT + l16 * 8 + 4) = o1;
  }
}

extern "C" void kernel_launch(void* const* d_in, const int* in_sizes, int n_in,
                              void* d_out, int out_size, void* d_ws, size_t ws_size,
                              hipStream_t stream) {
  const float* x     = (const float*)d_in[0];
  const int* ei      = (const int*)d_in[1];
  const int* etype   = (const int*)d_in[2];
  const float* rel   = (const float*)d_in[3];
  const float* W1    = (const float*)d_in[4];
  const float* at_s1 = (const float*)d_in[5];
  const float* at_d1 = (const float*)d_in[6];
  const float* b1    = (const float*)d_in[7];
  const float* W2    = (const float*)d_in[8];
  const float* at_s2 = (const float*)d_in[9];
  const float* at_d2 = (const float*)d_in[10];
  const float* b2v   = (const float*)d_in[11];
  float* out         = (float*)d_out;

  const int N = in_sizes[0] / D_IN;  // 20000
  const int E = in_sizes[2];         // 640000
  const int* srcv = ei;
  const int* dstv = ei + E;

  char* p = (char*)d_ws;
  auto carve = [&](size_t bytes) -> char* {
    char* r = p; p += (bytes + 255) & ~(size_t)255; return r;
  };
  // contiguous int-scratch region (single memset)
  int*   counts  = (int*)carve((size_t)N * NREL * 4);
  int*   deg     = (int*)carve((size_t)N * 4);
  int*   offsets = (int*)carve(((size_t)N + 1) * 4);
  int*   cursor  = (int*)carve((size_t)N * 4);
  int*   bsum    = (int*)carve(64 * 4);
  size_t int_scratch_bytes = (size_t)(p - (char*)counts);
  int*   csr_src = (int*)carve((size_t)E * 4);
  float* as1     = (float*)carve((size_t)N * NHEADS * 4);
  float* ad1     = (float*)carve((size_t)N * NHEADS * 4);
  float* as2     = (float*)carve((size_t)N * 4);
  float* ad2     = (float*)carve((size_t)N * 4);
  unsigned short* W1T    = (unsigned short*)carve((size_t)HID1 * D_IN * 2);
  unsigned short* W2T    = (unsigned short*)carve((size_t)DOUT * HID1 * 2);
  unsigned short* x_modb = (unsigned short*)carve((size_t)M_PAD * D_IN * 2);
  unsigned short* h1b    = (unsigned short*)carve((size_t)M_PAD * HID1 * 2);
  unsigned short* h2b    = (unsigned short*)carve((size_t)M_PAD * HID1 * 2);
  unsigned short* t2b    = (unsigned short*)carve((size_t)M_PAD * DOUT * 2);

  hipMemsetAsync(counts, 0, int_scratch_bytes, stream);

  int eb = (E + 255) / 256;
  int nb = (N + 1023) / 1024;  // 20
  count_kernel<<<eb, 256, 0, stream>>>(srcv, dstv, etype, counts, deg, E);
  scan_local<<<nb, 256, 0, stream>>>(deg, offsets, bsum, N);
  scan_blocks<<<1, 64, 0, stream>>>(bsum, nb, offsets, N);
  scan_add<<<nb, 256, 0, stream>>>(offsets, bsum, N);
  scatter_kernel<<<eb, 256, 0, stream>>>(srcv, dstv, offsets, cursor, csr_src, E);
  castT_both<<<(D_IN * HID1 + HID1 * DOUT + 255) / 256, 256, 0, stream>>>(W1, W2, W1T, W2T);
  xmod_kernel<<<N, 256, 0, stream>>>(x, counts, rel, x_modb, N);
  mfma_gemm<128><<<dim3(HID1 / 128, M_PAD / 128), 256, 0, stream>>>(x_modb, W1T, h1b, N, HID1, D_IN);
  alpha1_kernel<<<N, 256, 0, stream>>>(h1b, at_s1, at_d1, as1, ad1, N);
  aggregate1_kernel<<<(N + 3) / 4, 256, 0, stream>>>(h1b, as1, ad1, offsets, csr_src, b1, h2b, N);
  mfma_gemm<64><<<dim3(DOUT / 128, M_PAD / 64), 256, 0, stream>>>(h2b, W2T, t2b, N, DOUT, HID1);
  alpha2_kernel<<<(N + 3) / 4, 256, 0, stream>>>(t2b, at_s2, at_d2, as2, ad2, N);
  aggregate2_kernel<<<(N + 3) / 4, 256, 0, stream>>>(t2b, as2, ad2, offsets, csr_src, b2v, out, N);
}

// Round 6
// 383.578 us; speedup vs baseline: 1.7437x; 1.0128x over previous
//
#include <hip/hip_runtime.h>

// N=20000, E=640000, D_IN=256, HID1=512 (4 heads x 128), D_OUT=128, R=32.
// fp32 inputs/outputs; internal h1/h2/t2/x_mod bf16 (gather traffic + MFMA).
// alpha dots fused into GEMM epilogues; offsets carried as (local + bsum[blk]).

#define D_IN   256
#define HID1   512
#define NHEADS 4
#define CH1    128
#define DOUT   128
#define NREL   32
#define NEG_SLOPE 0.2f
#define M_PAD  20096   // 157*128 == 314*64

static __device__ __forceinline__ float b2f(unsigned short u) {
  union { unsigned int i; float f; } v; v.i = ((unsigned int)u) << 16; return v.f;
}
static __device__ __forceinline__ unsigned short f2b(float f) {
  union { float f; unsigned int i; } v; v.f = f;
  unsigned int x = v.i;
  return (unsigned short)((x + 0x7fffu + ((x >> 16) & 1u)) >> 16);
}
static __device__ __forceinline__ float lrelu(float x) {
  return x > 0.f ? x : NEG_SLOPE * x;
}

typedef __attribute__((ext_vector_type(8))) short bf16x8;
typedef __attribute__((ext_vector_type(4))) float f32x4;

// ---- prep: edge counting + weight cast/transpose in one launch ------------
__global__ void prep_kernel(const int* __restrict__ src, const int* __restrict__ dst,
                            const int* __restrict__ et, int* __restrict__ counts,
                            int* __restrict__ deg, int E, int eb,
                            const float* __restrict__ W1, const float* __restrict__ W2,
                            unsigned short* __restrict__ W1T, unsigned short* __restrict__ W2T) {
  int b = blockIdx.x;
  if (b < eb) {
    int e = b * 256 + threadIdx.x;
    if (e >= E) return;
    atomicAdd(&counts[(size_t)src[e] * NREL + et[e]], 1);
    atomicAdd(&deg[dst[e]], 1);
  } else {
    int idx = (b - eb) * 256 + threadIdx.x;
    if (idx < D_IN * HID1) {
      int r = idx / HID1, c = idx % HID1;
      W1T[(size_t)c * D_IN + r] = f2b(W1[idx]);
    } else {
      int k = idx - D_IN * HID1;
      if (k < HID1 * DOUT) {
        int r = k / DOUT, c = k % DOUT;
        W2T[(size_t)c * HID1 + r] = f2b(W2[k]);
      }
    }
  }
}

// ---- scan: per-block local exclusive scan + block sums --------------------
__global__ void scan_local(const int* __restrict__ in, int* __restrict__ out,
                           int* __restrict__ bsum, int n) {
  __shared__ int wsum[4];
  int t = threadIdx.x;
  int base = blockIdx.x * 1024 + t * 4;
  int v0 = (base + 0 < n) ? in[base + 0] : 0;
  int v1 = (base + 1 < n) ? in[base + 1] : 0;
  int v2 = (base + 2 < n) ? in[base + 2] : 0;
  int v3 = (base + 3 < n) ? in[base + 3] : 0;
  int s = v0 + v1 + v2 + v3;
  int lane = t & 63, w = t >> 6;
  int sc = s;
  for (int off = 1; off < 64; off <<= 1) {
    int u = __shfl_up(sc, off);
    if (lane >= off) sc += u;
  }
  if (lane == 63) wsum[w] = sc;
  __syncthreads();
  int woff = 0;
  for (int i = 0; i < w; ++i) woff += wsum[i];
  int excl = woff + sc - s;
  if (base + 0 < n) out[base + 0] = excl;
  if (base + 1 < n) out[base + 1] = excl + v0;
  if (base + 2 < n) out[base + 2] = excl + v0 + v1;
  if (base + 3 < n) out[base + 3] = excl + v0 + v1 + v2;
  if (t == 255) bsum[blockIdx.x] = woff + sc;
}

// bsum -> exclusive prefix; offsets[n] set so offsets[n]+bsum[n>>10] == total
__global__ void scan_blocks(int* __restrict__ bsum, int nb,
                            int* __restrict__ offsets, int n) {
  int t = threadIdx.x;  // 64
  int v = (t < nb) ? bsum[t] : 0;
  int sc = v;
  for (int off = 1; off < 64; off <<= 1) {
    int u = __shfl_up(sc, off);
    if (t >= off) sc += u;
  }
  if (t < nb) bsum[t] = sc - v;
  if (t == nb - 1) offsets[n] = v;  // total - excl[nb-1] == v
}

__global__ void scatter_kernel(const int* __restrict__ src, const int* __restrict__ dst,
                               const int* __restrict__ offsets, const int* __restrict__ bsum,
                               int* __restrict__ cursor, int* __restrict__ csr_src, int E) {
  int e = blockIdx.x * 256 + threadIdx.x;
  if (e >= E) return;
  int d = dst[e];
  int pos = offsets[d] + bsum[d >> 10] + atomicAdd(&cursor[d], 1);
  csr_src[pos] = src[e];
}

// ---- x_mod ----------------------------------------------------------------
__global__ void xmod_kernel(const float* __restrict__ x,
                            const int* __restrict__ counts,
                            const float* __restrict__ rel,
                            unsigned short* __restrict__ x_modb, int n_nodes) {
  __shared__ int cnt[NREL];
  int node = blockIdx.x;
  if (threadIdx.x < NREL) cnt[threadIdx.x] = counts[(size_t)node * NREL + threadIdx.x];
  __syncthreads();
  int k = threadIdx.x;
  float v = x[(size_t)node * D_IN + k];
  for (int r = 0; r < NREL; ++r) {
    int c = cnt[r];
    if (c) v += (float)c * rel[r * D_IN + k];
  }
  x_modb[(size_t)node * D_IN + k] = f2b(v);
}

// ---- bf16 MFMA GEMM + fused alpha epilogue --------------------------------
// Col-block = 128 cols = one head's channels (head = blockIdx.x).
// Epilogue computes per-row dot(row, att_s[head]) / dot(row, att_d[head])
// fully in-block (shfl over l16, atomicAdd across the 2 col-half waves).
template <int BM, int NH>
__global__ __launch_bounds__(256) void mfma_gemm(
    const unsigned short* __restrict__ A, const unsigned short* __restrict__ BT,
    unsigned short* __restrict__ C, int M, int N, int K,
    const float* __restrict__ att_s, const float* __restrict__ att_d,
    float* __restrict__ as_out, float* __restrict__ ad_out) {
  constexpr int MFR = BM / 32;
  __shared__ __align__(16) unsigned short Asl[BM * 32];
  __shared__ __align__(16) unsigned short Bsl[128 * 32];
  int tid = threadIdx.x;
  int m0 = blockIdx.y * BM, n0 = blockIdx.x * 128;
  int lane = tid & 63, wv = tid >> 6;
  int wm = wv & 1, wn = wv >> 1;
  int l16 = lane & 15, quad = lane >> 4;
  int lr = lane >> 2, lseg = lane & 3;

  f32x4 acc[MFR][4];
#pragma unroll
  for (int i = 0; i < MFR; ++i)
#pragma unroll
    for (int j = 0; j < 4; ++j) acc[i][j] = (f32x4)(0.f);

  for (int k0 = 0; k0 < K; k0 += 32) {
#pragma unroll
    for (int c = wv; c < BM / 16; c += 4) {
      int gr = m0 + c * 16 + lr; gr = gr < M ? gr : M - 1;
      __builtin_amdgcn_global_load_lds(
          (const __attribute__((address_space(1))) void*)(A + (size_t)gr * K + k0 + lseg * 8),
          (__attribute__((address_space(3))) void*)(&Asl[c * 512]), 16, 0, 0);
    }
#pragma unroll
    for (int c = wv; c < 8; c += 4) {
      int gr = n0 + c * 16 + lr;
      __builtin_amdgcn_global_load_lds(
          (const __attribute__((address_space(1))) void*)(BT + (size_t)gr * K + k0 + lseg * 8),
          (__attribute__((address_space(3))) void*)(&Bsl[c * 512]), 16, 0, 0);
    }
    __syncthreads();
    bf16x8 af[MFR], bfr[4];
#pragma unroll
    for (int mf = 0; mf < MFR; ++mf)
      af[mf] = *(const bf16x8*)(&Asl[(wm * (BM / 2) + mf * 16 + l16) * 32 + quad * 8]);
#pragma unroll
    for (int nf = 0; nf < 4; ++nf)
      bfr[nf] = *(const bf16x8*)(&Bsl[(wn * 64 + nf * 16 + l16) * 32 + quad * 8]);
#pragma unroll
    for (int mf = 0; mf < MFR; ++mf)
#pragma unroll
      for (int nf = 0; nf < 4; ++nf)
        acc[mf][nf] = __builtin_amdgcn_mfma_f32_16x16x32_bf16(af[mf], bfr[nf], acc[mf][nf], 0, 0, 0);
    __syncthreads();
  }
  // C write
#pragma unroll
  for (int mf = 0; mf < MFR; ++mf)
#pragma unroll
    for (int nf = 0; nf < 4; ++nf)
#pragma unroll
      for (int r = 0; r < 4; ++r) {
        int row = m0 + wm * (BM / 2) + mf * 16 + quad * 4 + r;
        int col = n0 + wn * 64 + nf * 16 + l16;
        C[(size_t)row * N + col] = f2b(acc[mf][nf][r]);
      }
  // fused alpha epilogue
  int head = blockIdx.x;  // col-block == head block (N per head == 128)
  float asw[4], adw[4];
#pragma unroll
  for (int nf = 0; nf < 4; ++nf) {
    int cl = wn * 64 + nf * 16 + l16;  // 0..127 within head
    asw[nf] = att_s[head * 128 + cl];
    adw[nf] = att_d[head * 128 + cl];
  }
#pragma unroll
  for (int mf = 0; mf < MFR; ++mf)
#pragma unroll
    for (int r = 0; r < 4; ++r) {
      float sd = acc[mf][0][r] * asw[0] + acc[mf][1][r] * asw[1] +
                 acc[mf][2][r] * asw[2] + acc[mf][3][r] * asw[3];
      float dd = acc[mf][0][r] * adw[0] + acc[mf][1][r] * adw[1] +
                 acc[mf][2][r] * adw[2] + acc[mf][3][r] * adw[3];
#pragma unroll
      for (int off = 1; off < 16; off <<= 1) {
        sd += __shfl_xor(sd, off);
        dd += __shfl_xor(dd, off);
      }
      int row = m0 + wm * (BM / 2) + mf * 16 + quad * 4 + r;
      if (l16 == 0 && row < M) {
        atomicAdd(&as_out[row * NH + head], sd);
        atomicAdd(&ad_out[row * NH + head], dd);
      }
    }
}

// ---- layer-1 aggregate: one wave/node, 2 groups x 2-edge unroll -----------
__global__ __launch_bounds__(256) void aggregate1_kernel(
    const unsigned short* __restrict__ h1b,
    const float* __restrict__ as1, const float* __restrict__ ad1,
    const int* __restrict__ offsets, const int* __restrict__ bsum,
    const int* __restrict__ csr_src,
    const float* __restrict__ bias, unsigned short* __restrict__ h2b, int n_nodes) {
  int node = blockIdx.x * 4 + (threadIdx.x >> 6);
  if (node >= n_nodes) return;
  int lane = threadIdx.x & 63;
  int g = lane >> 5, l32 = lane & 31;
  int head = l32 >> 3;
  int lo = offsets[node] + bsum[node >> 10];
  int hi = offsets[node + 1] + bsum[(node + 1) >> 10];
  const float4* as1v = (const float4*)as1;
  float4 asn = as1v[node];
  float4 ad4 = ((const float4*)ad1)[node];
  float m0 = lrelu(asn.x + ad4.x), m1 = lrelu(asn.y + ad4.y);
  float m2 = lrelu(asn.z + ad4.z), m3 = lrelu(asn.w + ad4.w);
  for (int j = lo + lane; j < hi; j += 64) {
    float4 a = as1v[csr_src[j]];
    m0 = fmaxf(m0, lrelu(a.x + ad4.x)); m1 = fmaxf(m1, lrelu(a.y + ad4.y));
    m2 = fmaxf(m2, lrelu(a.z + ad4.z)); m3 = fmaxf(m3, lrelu(a.w + ad4.w));
  }
  for (int off = 32; off; off >>= 1) {
    m0 = fmaxf(m0, __shfl_xor(m0, off)); m1 = fmaxf(m1, __shfl_xor(m1, off));
    m2 = fmaxf(m2, __shfl_xor(m2, off)); m3 = fmaxf(m3, __shfl_xor(m3, off));
  }
  float m_own  = head == 0 ? m0 : head == 1 ? m1 : head == 2 ? m2 : m3;
  float ad_own = head == 0 ? ad4.x : head == 1 ? ad4.y : head == 2 ? ad4.z : ad4.w;
  float as_own = head == 0 ? asn.x : head == 1 ? asn.y : head == 2 ? asn.z : asn.w;

  const uint4* h1v = (const uint4*)h1b;
  float acc[16];
#pragma unroll
  for (int k = 0; k < 16; ++k) acc[k] = 0.f;
  float denom = 0.f;

  // group g handles edges lo+4i+g and lo+4i+2+g
  int nit = (hi - lo + 3) >> 2;
  int j0 = lo + g, j1 = lo + g + 2;
  bool v0 = j0 < hi, v1 = j1 < hi;
  int s0 = v0 ? csr_src[j0] : node;
  int s1 = v1 ? csr_src[j1] : node;
  float a0 = as1[s0 * 4 + head], a1 = as1[s1 * 4 + head];
  for (int i = 0; i < nit; ++i) {
    int j0n = j0 + 4, j1n = j1 + 4;
    bool v0n = j0n < hi, v1n = j1n < hi;
    int s0n = v0n ? csr_src[j0n] : node;
    int s1n = v1n ? csr_src[j1n] : node;
    float a0n = as1[s0n * 4 + head], a1n = as1[s1n * 4 + head];
    uint4 r00 = h1v[(size_t)s0 * 64 + l32 * 2];
    uint4 r01 = h1v[(size_t)s0 * 64 + l32 * 2 + 1];
    uint4 r10 = h1v[(size_t)s1 * 64 + l32 * 2];
    uint4 r11 = h1v[(size_t)s1 * 64 + l32 * 2 + 1];
    float w0 = v0 ? __expf(lrelu(a0 + ad_own) - m_own) : 0.f;
    float w1 = v1 ? __expf(lrelu(a1 + ad_own) - m_own) : 0.f;
    unsigned int u;
    union { unsigned int i; float f; } cl, ch;
    u = r00.x; cl.i = u << 16; ch.i = u & 0xffff0000u; acc[0]  += w0 * cl.f; acc[1]  += w0 * ch.f;
    u = r00.y; cl.i = u << 16; ch.i = u & 0xffff0000u; acc[2]  += w0 * cl.f; acc[3]  += w0 * ch.f;
    u = r00.z; cl.i = u << 16; ch.i = u & 0xffff0000u; acc[4]  += w0 * cl.f; acc[5]  += w0 * ch.f;
    u = r00.w; cl.i = u << 16; ch.i = u & 0xffff0000u; acc[6]  += w0 * cl.f; acc[7]  += w0 * ch.f;
    u = r01.x; cl.i = u << 16; ch.i = u & 0xffff0000u; acc[8]  += w0 * cl.f; acc[9]  += w0 * ch.f;
    u = r01.y; cl.i = u << 16; ch.i = u & 0xffff0000u; acc[10] += w0 * cl.f; acc[11] += w0 * ch.f;
    u = r01.z; cl.i = u << 16; ch.i = u & 0xffff0000u; acc[12] += w0 * cl.f; acc[13] += w0 * ch.f;
    u = r01.w; cl.i = u << 16; ch.i = u & 0xffff0000u; acc[14] += w0 * cl.f; acc[15] += w0 * ch.f;
    u = r10.x; cl.i = u << 16; ch.i = u & 0xffff0000u; acc[0]  += w1 * cl.f; acc[1]  += w1 * ch.f;
    u = r10.y; cl.i = u << 16; ch.i = u & 0xffff0000u; acc[2]  += w1 * cl.f; acc[3]  += w1 * ch.f;
    u = r10.z; cl.i = u << 16; ch.i = u & 0xffff0000u; acc[4]  += w1 * cl.f; acc[5]  += w1 * ch.f;
    u = r10.w; cl.i = u << 16; ch.i = u & 0xffff0000u; acc[6]  += w1 * cl.f; acc[7]  += w1 * ch.f;
    u = r11.x; cl.i = u << 16; ch.i = u & 0xffff0000u; acc[8]  += w1 * cl.f; acc[9]  += w1 * ch.f;
    u = r11.y; cl.i = u << 16; ch.i = u & 0xffff0000u; acc[10] += w1 * cl.f; acc[11] += w1 * ch.f;
    u = r11.z; cl.i = u << 16; ch.i = u & 0xffff0000u; acc[12] += w1 * cl.f; acc[13] += w1 * ch.f;
    u = r11.w; cl.i = u << 16; ch.i = u & 0xffff0000u; acc[14] += w1 * cl.f; acc[15] += w1 * ch.f;
    denom += w0 + w1;
    j0 = j0n; j1 = j1n; v0 = v0n; v1 = v1n; s0 = s0n; s1 = s1n; a0 = a0n; a1 = a1n;
  }
  if (g == 0) {  // self loop
    uint4 h0 = h1v[(size_t)node * 64 + l32 * 2];
    uint4 h1r = h1v[(size_t)node * 64 + l32 * 2 + 1];
    float w = __expf(lrelu(as_own + ad_own) - m_own);
    unsigned int u;
    union { unsigned int i; float f; } cl, ch;
    u = h0.x; cl.i = u << 16; ch.i = u & 0xffff0000u; acc[0]  += w * cl.f; acc[1]  += w * ch.f;
    u = h0.y; cl.i = u << 16; ch.i = u & 0xffff0000u; acc[2]  += w * cl.f; acc[3]  += w * ch.f;
    u = h0.z; cl.i = u << 16; ch.i = u & 0xffff0000u; acc[4]  += w * cl.f; acc[5]  += w * ch.f;
    u = h0.w; cl.i = u << 16; ch.i = u & 0xffff0000u; acc[6]  += w * cl.f; acc[7]  += w * ch.f;
    u = h1r.x; cl.i = u << 16; ch.i = u & 0xffff0000u; acc[8]  += w * cl.f; acc[9]  += w * ch.f;
    u = h1r.y; cl.i = u << 16; ch.i = u & 0xffff0000u; acc[10] += w * cl.f; acc[11] += w * ch.f;
    u = h1r.z; cl.i = u << 16; ch.i = u & 0xffff0000u; acc[12] += w * cl.f; acc[13] += w * ch.f;
    u = h1r.w; cl.i = u << 16; ch.i = u & 0xffff0000u; acc[14] += w * cl.f; acc[15] += w * ch.f;
    denom += w;
  }
#pragma unroll
  for (int k = 0; k < 16; ++k) acc[k] += __shfl_xor(acc[k], 32);
  denom += __shfl_xor(denom, 32);
  if (g == 0) {
    float inv = 1.f / (denom + 1e-16f);
    unsigned int od[8];
#pragma unroll
    for (int q = 0; q < 8; ++q) {
      float vlo = acc[2 * q] * inv + bias[l32 * 16 + 2 * q];
      float vhi = acc[2 * q + 1] * inv + bias[l32 * 16 + 2 * q + 1];
      vlo = vlo > 0.f ? vlo : expm1f(vlo);
      vhi = vhi > 0.f ? vhi : expm1f(vhi);
      od[q] = (unsigned int)f2b(vlo) | ((unsigned int)f2b(vhi) << 16);
    }
    uint4 o0; o0.x = od[0]; o0.y = od[1]; o0.z = od[2]; o0.w = od[3];
    uint4 o1; o1.x = od[4]; o1.y = od[5]; o1.z = od[6]; o1.w = od[7];
    ((uint4*)h2b)[(size_t)node * 64 + l32 * 2] = o0;
    ((uint4*)h2b)[(size_t)node * 64 + l32 * 2 + 1] = o1;
  }
}

// ---- layer-2 aggregate: one wave/node, 4 groups x 2-edge unroll -----------
__global__ __launch_bounds__(256) void aggregate2_kernel(
    const unsigned short* __restrict__ t2b,
    const float* __restrict__ as2, const float* __restrict__ ad2,
    const int* __restrict__ offsets, const int* __restrict__ bsum,
    const int* __restrict__ csr_src,
    const float* __restrict__ bias, float* __restrict__ out, int n_nodes) {
  int node = blockIdx.x * 4 + (threadIdx.x >> 6);
  if (node >= n_nodes) return;
  int lane = threadIdx.x & 63;
  int g = lane >> 4, l16 = lane & 15;
  int lo = offsets[node] + bsum[node >> 10];
  int hi = offsets[node + 1] + bsum[(node + 1) >> 10];
  float ad = ad2[node];
  float e_self = lrelu(as2[node] + ad);
  float m = e_self;
  for (int j = lo + lane; j < hi; j += 64)
    m = fmaxf(m, lrelu(as2[csr_src[j]] + ad));
  for (int off = 32; off; off >>= 1) m = fmaxf(m, __shfl_xor(m, off));

  const uint4* t2v = (const uint4*)t2b;
  float acc[8] = {0.f, 0.f, 0.f, 0.f, 0.f, 0.f, 0.f, 0.f};
  float denom = 0.f;
  // group g handles edges lo+8i+g and lo+8i+4+g
  int nit = (hi - lo + 7) >> 3;
  int j0 = lo + g, j1 = lo + g + 4;
  bool v0 = j0 < hi, v1 = j1 < hi;
  int s0 = v0 ? csr_src[j0] : node;
  int s1 = v1 ? csr_src[j1] : node;
  float a0 = as2[s0], a1 = as2[s1];
  for (int i = 0; i < nit; ++i) {
    int j0n = j0 + 8, j1n = j1 + 8;
    bool v0n = j0n < hi, v1n = j1n < hi;
    int s0n = v0n ? csr_src[j0n] : node;
    int s1n = v1n ? csr_src[j1n] : node;
    float a0n = as2[s0n], a1n = as2[s1n];
    uint4 t0 = t2v[(size_t)s0 * 16 + l16];
    uint4 t1 = t2v[(size_t)s1 * 16 + l16];
    float w0 = v0 ? __expf(lrelu(a0 + ad) - m) : 0.f;
    float w1 = v1 ? __expf(lrelu(a1 + ad) - m) : 0.f;
    unsigned int u;
    union { unsigned int i; float f; } cl, ch;
    u = t0.x; cl.i = u << 16; ch.i = u & 0xffff0000u; acc[0] += w0 * cl.f; acc[1] += w0 * ch.f;
    u = t0.y; cl.i = u << 16; ch.i = u & 0xffff0000u; acc[2] += w0 * cl.f; acc[3] += w0 * ch.f;
    u = t0.z; cl.i = u << 16; ch.i = u & 0xffff0000u; acc[4] += w0 * cl.f; acc[5] += w0 * ch.f;
    u = t0.w; cl.i = u << 16; ch.i = u & 0xffff0000u; acc[6] += w0 * cl.f; acc[7] += w0 * ch.f;
    u = t1.x; cl.i = u << 16; ch.i = u & 0xffff0000u; acc[0] += w1 * cl.f; acc[1] += w1 * ch.f;
    u = t1.y; cl.i = u << 16; ch.i = u & 0xffff0000u; acc[2] += w1 * cl.f; acc[3] += w1 * ch.f;
    u = t1.z; cl.i = u << 16; ch.i = u & 0xffff0000u; acc[4] += w1 * cl.f; acc[5] += w1 * ch.f;
    u = t1.w; cl.i = u << 16; ch.i = u & 0xffff0000u; acc[6] += w1 * cl.f; acc[7] += w1 * ch.f;
    denom += w0 + w1;
    j0 = j0n; j1 = j1n; v0 = v0n; v1 = v1n; s0 = s0n; s1 = s1n; a0 = a0n; a1 = a1n;
  }
  if (g == 0) {  // self loop
    uint4 tv = t2v[(size_t)node * 16 + l16];
    float w = __expf(e_self - m);
    unsigned int u;
    union { unsigned int i; float f; } cl, ch;
    u = tv.x; cl.i = u << 16; ch.i = u & 0xffff0000u; acc[0] += w * cl.f; acc[1] += w * ch.f;
    u = tv.y; cl.i = u << 16; ch.i = u & 0xffff0000u; acc[2] += w * cl.f; acc[3] += w * ch.f;
    u = tv.z; cl.i = u << 16; ch.i = u & 0xffff0000u; acc[4] += w * cl.f; acc[5] += w * ch.f;
    u = tv.w; cl.i = u << 16; ch.i = u & 0xffff0000u; acc[6] += w * cl.f; acc[7] += w * ch.f;
    denom += w;
  }
#pragma unroll
  for (int k = 0; k < 8; ++k) {
    acc[k] += __shfl_xor(acc[k], 16);
    acc[k] += __shfl_xor(acc[k], 32);
  }
  denom += __shfl_xor(denom, 16);
  denom += __shfl_xor(denom, 32);
  if (g == 0) {
    float inv = 1.f / (denom + 1e-16f);
    float4 o0, o1;
    o0.x = acc[0] * inv + bias[l16 * 8 + 0];
    o0.y = acc[1] * inv + bias[l16 * 8 + 1];
    o0.z = acc[2] * inv + bias[l16 * 8 + 2];
    o0.w = acc[3] * inv + bias[l16 * 8 + 3];
    o1.x = acc[4] * inv + bias[l16 * 8 + 4];
    o1.y = acc[5] * inv + bias[l16 * 8 + 5];
    o1.z = acc[6] * inv + bias[l16 * 8 + 6];
    o1.w = acc[7] * inv + bias[l16 * 8 + 7];
    *(float4*)(out + (size_t)node * DOUT + l16 * 8) = o0;
    *(float4*)(out + (size_t)node * DOUT + l16 * 8 + 4) = o1;
  }
}

extern "C" void kernel_launch(void* const* d_in, const int* in_sizes, int n_in,
                              void* d_out, int out_size, void* d_ws, size_t ws_size,
                              hipStream_t stream) {
  const float* x     = (const float*)d_in[0];
  const int* ei      = (const int*)d_in[1];
  const int* etype   = (const int*)d_in[2];
  const float* rel   = (const float*)d_in[3];
  const float* W1    = (const float*)d_in[4];
  const float* at_s1 = (const float*)d_in[5];
  const float* at_d1 = (const float*)d_in[6];
  const float* b1    = (const float*)d_in[7];
  const float* W2    = (const float*)d_in[8];
  const float* at_s2 = (const float*)d_in[9];
  const float* at_d2 = (const float*)d_in[10];
  const float* b2v   = (const float*)d_in[11];
  float* out         = (float*)d_out;

  const int N = in_sizes[0] / D_IN;  // 20000
  const int E = in_sizes[2];         // 640000
  const int* srcv = ei;
  const int* dstv = ei + E;

  char* p = (char*)d_ws;
  auto carve = [&](size_t bytes) -> char* {
    char* r = p; p += (bytes + 255) & ~(size_t)255; return r;
  };
  // zeroed scratch region (single memset): counters + alpha accumulators
  int*   counts  = (int*)carve((size_t)N * NREL * 4);
  int*   deg     = (int*)carve((size_t)N * 4);
  int*   offsets = (int*)carve(((size_t)N + 1) * 4);
  int*   cursor  = (int*)carve((size_t)N * 4);
  int*   bsum    = (int*)carve(64 * 4);
  float* as1     = (float*)carve((size_t)N * NHEADS * 4);
  float* ad1     = (float*)carve((size_t)N * NHEADS * 4);
  float* as2     = (float*)carve((size_t)N * 4);
  float* ad2     = (float*)carve((size_t)N * 4);
  size_t zero_bytes = (size_t)(p - (char*)counts);
  int*   csr_src = (int*)carve((size_t)E * 4);
  unsigned short* W1T    = (unsigned short*)carve((size_t)HID1 * D_IN * 2);
  unsigned short* W2T    = (unsigned short*)carve((size_t)DOUT * HID1 * 2);
  unsigned short* x_modb = (unsigned short*)carve((size_t)M_PAD * D_IN * 2);
  unsigned short* h1b    = (unsigned short*)carve((size_t)M_PAD * HID1 * 2);
  unsigned short* h2b    = (unsigned short*)carve((size_t)M_PAD * HID1 * 2);
  unsigned short* t2b    = (unsigned short*)carve((size_t)M_PAD * DOUT * 2);

  hipMemsetAsync(counts, 0, zero_bytes, stream);

  int eb = (E + 255) / 256;                       // 2500
  int cb = (D_IN * HID1 + HID1 * DOUT + 255) / 256;  // 768
  int nb = (N + 1023) / 1024;                     // 20
  prep_kernel<<<eb + cb, 256, 0, stream>>>(srcv, dstv, etype, counts, deg, E, eb,
                                           W1, W2, W1T, W2T);
  scan_local<<<nb, 256, 0, stream>>>(deg, offsets, bsum, N);
  scan_blocks<<<1, 64, 0, stream>>>(bsum, nb, offsets, N);
  scatter_kernel<<<eb, 256, 0, stream>>>(srcv, dstv, offsets, bsum, cursor, csr_src, E);
  xmod_kernel<<<N, 256, 0, stream>>>(x, counts, rel, x_modb, N);
  mfma_gemm<128, NHEADS><<<dim3(HID1 / 128, M_PAD / 128), 256, 0, stream>>>(
      x_modb, W1T, h1b, N, HID1, D_IN, at_s1, at_d1, as1, ad1);
  aggregate1_kernel<<<(N + 3) / 4, 256, 0, stream>>>(h1b, as1, ad1, offsets, bsum,
                                                     csr_src, b1, h2b, N);
  mfma_gemm<64, 1><<<dim3(DOUT / 128, M_PAD / 64), 256, 0, stream>>>(
      h2b, W2T, t2b, N, DOUT, HID1, at_s2, at_d2, as2, ad2);
  aggregate2_kernel<<<(N + 3) / 4, 256, 0, stream>>>(t2b, as2, ad2, offsets, bsum,
                                                     csr_src, b2v, out, N);
}